// Round 11
// baseline (936.782 us; speedup 1.0000x reference)
//
#include <hip/hip_runtime.h>
#include <hip/hip_bf16.h>
#include <math.h>

#define N_ROWS 4096
#define DIM    256
#define LDQ    288
#define NLAYER 4
#define GN_CHUNKS 16

typedef __attribute__((ext_vector_type(8))) short bf16x8;
typedef __attribute__((ext_vector_type(4))) float f32x4;
typedef unsigned short us;

__device__ __forceinline__ us f2b(float f) {
  unsigned int u = __float_as_uint(f);
  unsigned int r = (u + 0x7fffu + ((u >> 16) & 1u)) >> 16;
  return (us)r;
}
__device__ __forceinline__ float b2f(us b) {
  return __uint_as_float(((unsigned int)b) << 16);
}
__device__ __forceinline__ bf16x8 f8_to_b8(float4 a, float4 b) {
  bf16x8 r;
  r[0] = (short)f2b(a.x);
  r[1] = (short)f2b(a.y);
  r[2] = (short)f2b(a.z);
  r[3] = (short)f2b(a.w);
  r[4] = (short)f2b(b.x);
  r[5] = (short)f2b(b.y);
  r[6] = (short)f2b(b.z);
  r[7] = (short)f2b(b.w);
  return r;
}

// ---------------------------------------------------------------------------
// MFMA NT GEMM: C[M,256](f32) = A(bf16,lda) @ B^T (+bias)(+res)
// B either bf16 (Bb) or f32 (Bf) — exactly one non-null.
// ---------------------------------------------------------------------------
__global__ __launch_bounds__(256) void mfma_nt_kernel(
    const us* __restrict__ A, int lda, const us* __restrict__ Bb,
    const float* __restrict__ Bf, const float* __restrict__ bias,
    const float* __restrict__ res, float* __restrict__ C) {
  __shared__ __align__(16) short Al[64 * 32];
  __shared__ __align__(16) short Bl[64 * 32];
  const int tid = threadIdx.x;
  const int wv = tid >> 6, lane = tid & 63;
  const int cl = lane & 15, gq = lane >> 4;
  const int wr = wv >> 1, wc = wv & 1;
  const int m0 = blockIdx.x * 64, n0 = blockIdx.y * 64;
  f32x4 acc[2][2];
#pragma unroll
  for (int mi = 0; mi < 2; ++mi)
#pragma unroll
    for (int ni = 0; ni < 2; ++ni) acc[mi][ni] = (f32x4){0.f, 0.f, 0.f, 0.f};
  for (int k0 = 0; k0 < DIM; k0 += 32) {
    __syncthreads();
    {
      int r = tid >> 2, c = tid & 3;
      *(bf16x8*)&Al[r * 32 + c * 8] =
          *(const bf16x8*)&A[(size_t)(m0 + r) * lda + k0 + c * 8];
      if (Bf) {
        float4 u = *(const float4*)&Bf[(size_t)(n0 + r) * DIM + k0 + c * 8];
        float4 v =
            *(const float4*)&Bf[(size_t)(n0 + r) * DIM + k0 + c * 8 + 4];
        *(bf16x8*)&Bl[r * 32 + c * 8] = f8_to_b8(u, v);
      } else {
        *(bf16x8*)&Bl[r * 32 + c * 8] =
            *(const bf16x8*)&Bb[(size_t)(n0 + r) * DIM + k0 + c * 8];
      }
    }
    __syncthreads();
    bf16x8 af[2], bfr[2];
#pragma unroll
    for (int mi = 0; mi < 2; ++mi)
      af[mi] = *(const bf16x8*)&Al[(wr * 32 + mi * 16 + cl) * 32 + gq * 8];
#pragma unroll
    for (int ni = 0; ni < 2; ++ni)
      bfr[ni] = *(const bf16x8*)&Bl[(wc * 32 + ni * 16 + cl) * 32 + gq * 8];
#pragma unroll
    for (int mi = 0; mi < 2; ++mi)
#pragma unroll
      for (int ni = 0; ni < 2; ++ni)
        acc[mi][ni] = __builtin_amdgcn_mfma_f32_16x16x32_bf16(
            af[mi], bfr[ni], acc[mi][ni], 0, 0, 0);
  }
#pragma unroll
  for (int mi = 0; mi < 2; ++mi)
#pragma unroll
    for (int ni = 0; ni < 2; ++ni)
#pragma unroll
      for (int i = 0; i < 4; ++i) {
        int row = m0 + wr * 32 + mi * 16 + gq * 4 + i;
        int col = n0 + wc * 32 + ni * 16 + cl;
        float v = acc[mi][ni][i];
        if (bias) v += bias[col];
        if (res) v += res[(size_t)row * DIM + col];
        C[(size_t)row * DIM + col] = v;
      }
}

// ---------------------------------------------------------------------------
// Fused QKV MFMA: A f32, W f32 (converted in staging); bf16 outputs
// ---------------------------------------------------------------------------
__global__ __launch_bounds__(256) void mfma_qkv_kernel(
    const float* __restrict__ A, const float* __restrict__ W0,
    const float* __restrict__ W1, const float* __restrict__ W2,
    const float* __restrict__ b0, const float* __restrict__ b1,
    const float* __restrict__ b2, us* __restrict__ O0, us* __restrict__ O1,
    us* __restrict__ O2) {
  const float* Bm = (blockIdx.z == 0) ? W0 : (blockIdx.z == 1) ? W1 : W2;
  const float* bias = (blockIdx.z == 0) ? b0 : (blockIdx.z == 1) ? b1 : b2;
  us* Ob = (blockIdx.z == 0) ? O0 : (blockIdx.z == 1) ? O1 : O2;
  const int ldo = (blockIdx.z == 2) ? DIM : LDQ;
  __shared__ __align__(16) short Al[64 * 32];
  __shared__ __align__(16) short Bl[64 * 32];
  const int tid = threadIdx.x;
  const int wv = tid >> 6, lane = tid & 63;
  const int cl = lane & 15, gq = lane >> 4;
  const int wr = wv >> 1, wc = wv & 1;
  const int m0 = blockIdx.x * 64, n0 = blockIdx.y * 64;
  f32x4 acc[2][2];
#pragma unroll
  for (int mi = 0; mi < 2; ++mi)
#pragma unroll
    for (int ni = 0; ni < 2; ++ni) acc[mi][ni] = (f32x4){0.f, 0.f, 0.f, 0.f};
  for (int k0 = 0; k0 < DIM; k0 += 32) {
    __syncthreads();
    {
      int r = tid >> 2, c = tid & 3;
      float4 ua = *(const float4*)&A[(size_t)(m0 + r) * DIM + k0 + c * 8];
      float4 va = *(const float4*)&A[(size_t)(m0 + r) * DIM + k0 + c * 8 + 4];
      *(bf16x8*)&Al[r * 32 + c * 8] = f8_to_b8(ua, va);
      float4 ub = *(const float4*)&Bm[(size_t)(n0 + r) * DIM + k0 + c * 8];
      float4 vb = *(const float4*)&Bm[(size_t)(n0 + r) * DIM + k0 + c * 8 + 4];
      *(bf16x8*)&Bl[r * 32 + c * 8] = f8_to_b8(ub, vb);
    }
    __syncthreads();
    bf16x8 af[2], bfr[2];
#pragma unroll
    for (int mi = 0; mi < 2; ++mi)
      af[mi] = *(const bf16x8*)&Al[(wr * 32 + mi * 16 + cl) * 32 + gq * 8];
#pragma unroll
    for (int ni = 0; ni < 2; ++ni)
      bfr[ni] = *(const bf16x8*)&Bl[(wc * 32 + ni * 16 + cl) * 32 + gq * 8];
#pragma unroll
    for (int mi = 0; mi < 2; ++mi)
#pragma unroll
      for (int ni = 0; ni < 2; ++ni)
        acc[mi][ni] = __builtin_amdgcn_mfma_f32_16x16x32_bf16(
            af[mi], bfr[ni], acc[mi][ni], 0, 0, 0);
  }
#pragma unroll
  for (int mi = 0; mi < 2; ++mi)
#pragma unroll
    for (int ni = 0; ni < 2; ++ni)
#pragma unroll
      for (int i = 0; i < 4; ++i) {
        int row = m0 + wr * 32 + mi * 16 + gq * 4 + i;
        int col = n0 + wc * 32 + ni * 16 + cl;
        Ob[(size_t)row * ldo + col] = f2b(acc[mi][ni][i] + bias[col]);
      }
}

// ---------------------------------------------------------------------------
// Mpart[z] = Kt[:, z*512:+512] @ same^T (Kt bf16 [256][4096])
// ---------------------------------------------------------------------------
__global__ __launch_bounds__(256) void mpart_mfma_kernel(
    const us* __restrict__ Kt, float* __restrict__ Mp) {
  __shared__ __align__(16) short Al[64 * 32];
  __shared__ __align__(16) short Bl[64 * 32];
  const int tid = threadIdx.x;
  const int wv = tid >> 6, lane = tid & 63;
  const int cl = lane & 15, gq = lane >> 4;
  const int wr = wv >> 1, wc = wv & 1;
  const int a0 = blockIdx.x * 64, b0 = blockIdx.y * 64;
  const int kb = blockIdx.z * 512;
  f32x4 acc[2][2];
#pragma unroll
  for (int mi = 0; mi < 2; ++mi)
#pragma unroll
    for (int ni = 0; ni < 2; ++ni) acc[mi][ni] = (f32x4){0.f, 0.f, 0.f, 0.f};
  for (int k0 = 0; k0 < 512; k0 += 32) {
    __syncthreads();
    {
      int r = tid >> 2, c = tid & 3;
      *(bf16x8*)&Al[r * 32 + c * 8] =
          *(const bf16x8*)&Kt[(size_t)(a0 + r) * N_ROWS + kb + k0 + c * 8];
      *(bf16x8*)&Bl[r * 32 + c * 8] =
          *(const bf16x8*)&Kt[(size_t)(b0 + r) * N_ROWS + kb + k0 + c * 8];
    }
    __syncthreads();
    bf16x8 af[2], bfr[2];
#pragma unroll
    for (int mi = 0; mi < 2; ++mi)
      af[mi] = *(const bf16x8*)&Al[(wr * 32 + mi * 16 + cl) * 32 + gq * 8];
#pragma unroll
    for (int ni = 0; ni < 2; ++ni)
      bfr[ni] = *(const bf16x8*)&Bl[(wc * 32 + ni * 16 + cl) * 32 + gq * 8];
#pragma unroll
    for (int mi = 0; mi < 2; ++mi)
#pragma unroll
      for (int ni = 0; ni < 2; ++ni)
        acc[mi][ni] = __builtin_amdgcn_mfma_f32_16x16x32_bf16(
            af[mi], bfr[ni], acc[mi][ni], 0, 0, 0);
  }
#pragma unroll
  for (int mi = 0; mi < 2; ++mi)
#pragma unroll
    for (int ni = 0; ni < 2; ++ni)
#pragma unroll
      for (int i = 0; i < 4; ++i) {
        int row = a0 + wr * 32 + mi * 16 + gq * 4 + i;
        int col = b0 + wc * 32 + ni * 16 + cl;
        Mp[(size_t)blockIdx.z * 65536 + (size_t)row * DIM + col] =
            acc[mi][ni][i];
      }
}

__global__ void mreduce_kernel(const float* __restrict__ Mp,
                               us* __restrict__ Mb) {
  int e = blockIdx.x * 256 + threadIdx.x;
  float s = 0.f;
#pragma unroll
  for (int z = 0; z < 8; ++z) s += Mp[(size_t)z * 65536 + e];
  Mb[e] = f2b(s);
}

// ---------------------------------------------------------------------------
__global__ void ksum_part_kernel(const us* __restrict__ K,
                                 float* __restrict__ kpart) {
  int d = threadIdx.x, b = blockIdx.x;
  float s = 0.f;
  int base = b * 64;
  for (int n = 0; n < 64; ++n) s += b2f(K[(size_t)(base + n) * LDQ + d]);
  kpart[b * DIM + d] = s;
}
__global__ void ksum_red_kernel(const float* __restrict__ kpart,
                                float* __restrict__ ksum) {
  int d = threadIdx.x;
  float s = 0.f;
  for (int b = 0; b < 64; ++b) s += kpart[b * DIM + d];
  ksum[d] = s;
}

// ---------------------------------------------------------------------------
// stats: per-row mean/istd -> c1,cA; writes Qhat/Khat tails, Vhat tail rows,
// colB. grid 1024 x 256 (wave per row)
// ---------------------------------------------------------------------------
__global__ __launch_bounds__(256) void stats_kernel(
    us* __restrict__ Qh, us* __restrict__ Kh, us* __restrict__ Vtb,
    const float* __restrict__ tb, const float* __restrict__ ksum,
    const float* __restrict__ xyzc, const float* __restrict__ logy,
    const int* __restrict__ tptr, const float* __restrict__ bwp,
    const int* __restrict__ usestdp, float* __restrict__ c1a,
    float* __restrict__ cAa, float* __restrict__ colB) {
  const int wave = threadIdx.x >> 6, lane = threadIdx.x & 63;
  const int row = blockIdx.x * 4 + wave;
  ushort4 q4 = *(const ushort4*)&Qh[(size_t)row * LDQ + lane * 4];
  float qx = b2f(q4.x), qy = b2f(q4.y), qz = b2f(q4.z), qw = b2f(q4.w);
  const float4 tv4 = ((const float4*)(tb + (size_t)row * DIM))[lane];
  const float4 kv = ((const float4*)ksum)[lane];
  float p1 = qx * kv.x + qy * kv.y + qz * kv.z + qw * kv.w;
  float p2 = tv4.x * qx + tv4.y * qy + tv4.z * qz + tv4.w * qw;
#pragma unroll
  for (int off = 32; off >= 1; off >>= 1) {
    p1 += __shfl_xor(p1, off);
    p2 += __shfl_xor(p2, off);
  }
  float tt = (float)tptr[0];
  float sc = 1.f / (16.f * tt);
  float mean = p1 * sc * (1.f / (float)N_ROWS);
  float e2 = p2 * sc * sc * (1.f / (float)N_ROWS);
  float var = fmaxf(e2 - mean * mean, 0.f);
  float istd = 1.f / (sqrtf(var) + 1e-5f);
  int usestd = usestdp[0];
  float c1 = usestd ? sc * istd : sc;
  float c2 = usestd ? -mean * istd : 0.f;
  float bw = bwp[0];
  float i2 = 1.f / (2.f * bw * bw);
  float t2 = 2.f * i2;
  float x0 = xyzc[(size_t)row * 3 + 0];
  float x1 = xyzc[(size_t)row * 3 + 1];
  float x2 = xyzc[(size_t)row * 3 + 2];
  float sq = x0 * x0 + x1 * x1 + x2 * x2;
  if (lane == 0) {
    c1a[row] = c1;
    cAa[row] = c2 - sq * i2;
    colB[row] = logy[row] - sq * i2;
  }
  float qs = t2 / c1;
  if (lane < 32) {
    float v = (lane == 0) ? qs * x0
              : (lane == 1) ? qs * x1
              : (lane == 2) ? qs * x2
                            : 0.f;
    Qh[(size_t)row * LDQ + 256 + lane] = (lane < 3) ? f2b(v) : 0;
  } else {
    int j = lane - 32;
    float v = (j == 0) ? x0 : (j == 1) ? x1 : (j == 2) ? x2 : 0.f;
    Kh[(size_t)row * LDQ + 256 + j] = (j < 3) ? f2b(v) : 0;
  }
  if (lane < 16) {
    us v = 0;
    if (lane == 0) v = f2b(x0);
    else if (lane == 1) v = f2b(x1);
    else if (lane == 2) v = f2b(x2);
    else if (lane == 3) v = 0x3F80;  // 1.0
    Vtb[(size_t)(256 + lane) * N_ROWS + row] = v;
  }
}

__global__ void prep_kernel(const float* __restrict__ yhat,
                            float* __restrict__ logy) {
  int i = blockIdx.x * 256 + threadIdx.x;
  logy[i] = logf(yhat[i] + 1e-9f);
}

__global__ void maskpack_kernel(const int* __restrict__ dmask,
                                const int* __restrict__ bmask,
                                unsigned int* __restrict__ mbits) {
  int gid = blockIdx.x * 256 + threadIdx.x;
  bool v = (dmask[gid] != 0) && (bmask[gid] != 0);
  unsigned long long bal = __ballot(v);
  if ((threadIdx.x & 63) == 0) {
    int w = gid >> 5;
    mbits[w] = (unsigned int)(bal & 0xffffffffu);
    mbits[w + 1] = (unsigned int)(bal >> 32);
  }
}

// ---------------------------------------------------------------------------
// Transpose bf16 [4096, lda] (cols 0..255) -> bf16 [256][4096]
// ---------------------------------------------------------------------------
__global__ __launch_bounds__(256) void vt2_kernel(const us* __restrict__ inK,
                                                  const us* __restrict__ inV,
                                                  us* __restrict__ outK,
                                                  us* __restrict__ outV) {
  __shared__ us T[64][68];
  const us* in = (blockIdx.z == 0) ? inK : inV;
  us* out = (blockIdx.z == 0) ? outK : outV;
  const int lda = (blockIdx.z == 0) ? LDQ : DIM;
  const int n0 = blockIdx.x * 64, d0 = blockIdx.y * 64;
  const int tx = threadIdx.x & 63, ty = threadIdx.x >> 6;
#pragma unroll
  for (int p = 0; p < 16; ++p)
    T[ty + p * 4][tx] = in[(size_t)(n0 + ty + p * 4) * lda + d0 + tx];
  __syncthreads();
#pragma unroll
  for (int p = 0; p < 16; ++p)
    out[(size_t)(d0 + ty + p * 4) * N_ROWS + n0 + tx] = T[tx][ty + p * 4];
}

// ---------------------------------------------------------------------------
// Flash v6: 32 q-rows/wave, augmented operands; XCD-aware grid
// (blockIdx.x = split so all blocks of a split share one XCD's L2);
// T14 async staging (load next tile into regs before compute, ds_write after);
// coalesced partial writes via LDS re-assembly.
// grid (nsplit, 32), block 256 (4 waves).
// ---------------------------------------------------------------------------
__global__ __launch_bounds__(256, 2) void flash5_kernel(
    const us* __restrict__ Qh, const us* __restrict__ Kh,
    const us* __restrict__ Vtb, const float* __restrict__ colB,
    const float* __restrict__ c1a, const float* __restrict__ cAa,
    const unsigned int* __restrict__ mbits, const float* __restrict__ bwp,
    const int* __restrict__ selfdp, us* __restrict__ plo, us* __restrict__ phi,
    float* __restrict__ ps, float* __restrict__ paxlo,
    float* __restrict__ paxhi, int cps) {
  __shared__ __align__(16) short SMEM[22016];  // 44032 B
  short* Khl = SMEM;            // 1152*8
  short* Vhl = SMEM + 9216;     // 1088*8
  short* Pl = SMEM + 17920;     // 8*512

  const int tid = threadIdx.x;
  const int wv = tid >> 6, lane = tid & 63;
  const int cl = lane & 15, gq = lane >> 4;
  const int split = blockIdx.x;          // XCD = split % 8 (wgid = y*nsplit+x)
  const int R0 = blockIdx.y * 128 + wv * 32;
  const int colbase = split * cps;

  const float bw = bwp[0];
  const float i2 = 1.f / (2.f * bw * bw);
  const float sd2 = (float)selfdp[0] * i2;

  bf16x8 qa[2][9];
#pragma unroll
  for (int rt = 0; rt < 2; ++rt) {
    const bf16x8* qp = (const bf16x8*)(Qh + (size_t)(R0 + rt * 16 + cl) * LDQ);
#pragma unroll
    for (int ks = 0; ks < 9; ++ks) qa[rt][ks] = qp[ks * 4 + gq];
  }
  float c1v[2][4], cAv[2][4];
#pragma unroll
  for (int rt = 0; rt < 2; ++rt)
#pragma unroll
    for (int i = 0; i < 4; ++i) {
      int row = R0 + rt * 16 + gq * 4 + i;
      c1v[rt][i] = c1a[row];
      cAv[rt][i] = cAa[row];
    }
  f32x4 o[2][17];
#pragma unroll
  for (int rt = 0; rt < 2; ++rt)
#pragma unroll
    for (int dt = 0; dt < 17; ++dt) o[rt][dt] = (f32x4){0.f, 0.f, 0.f, 0.f};

  // T14 staging: global -> regs early, regs -> LDS late
  bf16x8 stg[9];
  auto load_tile = [&](int t0g) {
#pragma unroll
    for (int p = 0; p < 9; ++p) {
      int L = tid + p * 256;
      if (L < 1152) {
        int ks = L >> 7, ct = (L >> 6) & 1, g = (L >> 4) & 3, c = L & 15;
        stg[p] = *(const bf16x8*)&Kh[(size_t)(t0g + 2 * c + ct) * LDQ +
                                     ks * 32 + g * 8];
      } else if (L < 2240) {
        int L2 = L - 1152;
        int dt = L2 >> 6, g = (L2 >> 4) & 3, c = L2 & 15;
        stg[p] =
            *(const bf16x8*)&Vtb[(size_t)(dt * 16 + c) * N_ROWS + t0g + g * 8];
      }
    }
  };
  auto write_tile = [&]() {
#pragma unroll
    for (int p = 0; p < 9; ++p) {
      int L = tid + p * 256;
      if (L < 1152)
        *(bf16x8*)&Khl[L * 8] = stg[p];
      else if (L < 2240)
        *(bf16x8*)&Vhl[(L - 1152) * 8] = stg[p];
    }
  };

  load_tile(colbase);
  write_tile();
  __syncthreads();

  for (int tt = 0; tt < cps; tt += 32) {
    const int t0g = colbase + tt;
    const bool hasnext = (tt + 32 < cps);
    if (hasnext) load_tile(t0g + 32);  // latency hides under compute

    const int gc0 = t0g + 2 * cl;
    const float cb0 = colB[gc0];
    const float cb1 = colB[gc0 + 1];

#pragma unroll
    for (int rt = 0; rt < 2; ++rt) {
      f32x4 s0 = (f32x4){0.f, 0.f, 0.f, 0.f};
      f32x4 s1 = (f32x4){0.f, 0.f, 0.f, 0.f};
#pragma unroll
      for (int ks = 0; ks < 9; ++ks) {
        bf16x8 kf = *(const bf16x8*)&Khl[(ks * 128 + gq * 16 + cl) * 8];
        s0 = __builtin_amdgcn_mfma_f32_16x16x32_bf16(qa[rt][ks], kf, s0, 0, 0,
                                                     0);
      }
#pragma unroll
      for (int ks = 0; ks < 9; ++ks) {
        bf16x8 kf = *(const bf16x8*)&Khl[(ks * 128 + 64 + gq * 16 + cl) * 8];
        s1 = __builtin_amdgcn_mfma_f32_16x16x32_bf16(qa[rt][ks], kf, s1, 0, 0,
                                                     0);
      }
#pragma unroll
      for (int i = 0; i < 4; ++i) {
        int row = R0 + rt * 16 + gq * 4 + i;
        unsigned int mw = mbits[((size_t)row << 7) + (t0g >> 5)];
        unsigned int pm = (mw >> (2 * cl)) & 3u;
        float lg0 = fmaf(s0[i], c1v[rt][i], cAv[rt][i] + cb0);
        float lg1 = fmaf(s1[i], c1v[rt][i], cAv[rt][i] + cb1);
        if (row == gc0) lg0 -= sd2;
        if (row == gc0 + 1) lg1 -= sd2;
        lg0 = (pm & 1u) ? lg0 : -60.f;
        lg1 = (pm & 2u) ? lg1 : -60.f;
        float p0 = __expf(lg0);
        float p1 = __expf(lg1);
        unsigned int pk =
            (unsigned int)f2b(p0) | ((unsigned int)f2b(p1) << 16);
        *(unsigned int*)&Pl[(wv * 2 + rt) * 512 +
                            ((cl >> 2) * 16 + gq * 4 + i) * 8 + (cl & 3) * 2] =
            pk;
      }
    }
    bf16x8 pf0 = *(const bf16x8*)&Pl[(wv * 2 + 0) * 512 + (gq * 16 + cl) * 8];
    bf16x8 pf1 = *(const bf16x8*)&Pl[(wv * 2 + 1) * 512 + (gq * 16 + cl) * 8];
#pragma unroll
    for (int dt = 0; dt < 17; ++dt) {
      bf16x8 vf = *(const bf16x8*)&Vhl[(dt * 64 + gq * 16 + cl) * 8];
      o[0][dt] = __builtin_amdgcn_mfma_f32_16x16x32_bf16(pf0, vf, o[0][dt], 0,
                                                         0, 0);
      o[1][dt] = __builtin_amdgcn_mfma_f32_16x16x32_bf16(pf1, vf, o[1][dt], 0,
                                                         0, 0);
    }
    __syncthreads();  // all waves done reading this tile
    if (hasnext) {
      write_tile();
      __syncthreads();
    }
  }

  // epilogue: assemble o row-major in LDS, write coalesced 512B rows
  us* pb = (split < 8) ? plo : phi;
  float* paxb = (split < 8) ? paxlo : paxhi;
  const int sl = split & 7;
  short* obuf = SMEM + wv * 4096;  // 8 KB per wave
#pragma unroll
  for (int rt = 0; rt < 2; ++rt) {
#pragma unroll
    for (int dt = 0; dt < 16; ++dt)
#pragma unroll
      for (int i = 0; i < 4; ++i)
        obuf[(gq * 4 + i) * 256 + dt * 16 + cl] = (short)f2b(o[rt][dt][i]);
    // same-wave LDS ordering: reads below wait on writes above (lgkmcnt)
#pragma unroll
    for (int p = 0; p < 8; ++p) {
      int idx = p * 512 + lane * 8;
      int rl = idx >> 8;
      int col = idx & 255;
      bf16x8 v = *(const bf16x8*)&obuf[idx];
      *(bf16x8*)&pb[((size_t)sl * N_ROWS + R0 + rt * 16 + rl) * DIM + col] = v;
    }
#pragma unroll
    for (int i = 0; i < 4; ++i) {
      int row = R0 + rt * 16 + gq * 4 + i;
      float aug = o[rt][16][i];
      if (cl < 3)
        paxb[((size_t)sl * N_ROWS + row) * 3 + cl] = aug;
      else if (cl == 3)
        ps[(size_t)split * N_ROWS + row] = aug;
    }
  }
}

// ---------------------------------------------------------------------------
// Merge nsplit raw partials: O = (sum o_k)/(sum s_k); xyz update
// ---------------------------------------------------------------------------
__global__ __launch_bounds__(256) void merge_kernel(
    const us* __restrict__ plo, const us* __restrict__ phi,
    const float* __restrict__ ps, const float* __restrict__ paxlo,
    const float* __restrict__ paxhi, const float* __restrict__ xyzc,
    const float* __restrict__ betap, us* __restrict__ xattb,
    float* __restrict__ xyz_out, int nsplit) {
  const int wvl = threadIdx.x >> 6, lane = threadIdx.x & 63;
  const int row = blockIdx.x * 4 + wvl;
  float den = 0.f;
  for (int k = 0; k < nsplit; ++k) den += ps[(size_t)k * N_ROWS + row];
  float inv = 1.f / den;
  float a0 = 0.f, a1 = 0.f, a2 = 0.f, a3 = 0.f;
  float axs = 0.f;
  for (int k = 0; k < nsplit; ++k) {
    const us* pb = (k < 8) ? plo : phi;
    const us* p = &pb[((size_t)(k & 7) * N_ROWS + row) * DIM + lane * 4];
    uint2 u = *(const uint2*)p;
    a0 += __uint_as_float((u.x & 0xffffu) << 16);
    a1 += __uint_as_float(u.x & 0xffff0000u);
    a2 += __uint_as_float((u.y & 0xffffu) << 16);
    a3 += __uint_as_float(u.y & 0xffff0000u);
    if (lane < 3) {
      const float* paxb = (k < 8) ? paxlo : paxhi;
      axs += paxb[((size_t)(k & 7) * N_ROWS + row) * 3 + lane];
    }
  }
  ushort4 ov;
  ov.x = f2b(a0 * inv);
  ov.y = f2b(a1 * inv);
  ov.z = f2b(a2 * inv);
  ov.w = f2b(a3 * inv);
  *(ushort4*)&xattb[(size_t)row * DIM + lane * 4] = ov;
  if (lane < 3) {
    float beta = betap[0];
    xyz_out[(size_t)row * 3 + lane] =
        beta * axs * inv + (1.f - beta) * xyzc[(size_t)row * 3 + lane];
  }
}

// ---------------------------------------------------------------------------
// GraphNorm
// ---------------------------------------------------------------------------
__global__ __launch_bounds__(256) void gn_part_kernel(
    const float* __restrict__ X, const int* __restrict__ cums,
    float* __restrict__ gpart) {
  const int seg = blockIdx.x, chunk = blockIdx.y, d = threadIdx.x;
  const int r0 = cums[seg], r1 = cums[seg + 1];
  const int cnt = r1 - r0;
  const int per = (cnt + GN_CHUNKS - 1) / GN_CHUNKS;
  const int a = r0 + chunk * per;
  const int b = min(a + per, r1);
  float s = 0.f, ss = 0.f;
  for (int r = a; r < b; ++r) {
    float v = X[(size_t)r * DIM + d];
    s += v;
    ss += v * v;
  }
  gpart[(((size_t)seg * GN_CHUNKS + chunk) * 2 + 0) * DIM + d] = s;
  gpart[(((size_t)seg * GN_CHUNKS + chunk) * 2 + 1) * DIM + d] = ss;
}

__global__ void gn_red_kernel(const float* __restrict__ gpart,
                              const int* __restrict__ cums,
                              float* __restrict__ gm, float* __restrict__ gi) {
  const int seg = blockIdx.x, d = threadIdx.x;
  float s = 0.f, ss = 0.f;
#pragma unroll
  for (int c = 0; c < GN_CHUNKS; ++c) {
    s += gpart[(((size_t)seg * GN_CHUNKS + c) * 2 + 0) * DIM + d];
    ss += gpart[(((size_t)seg * GN_CHUNKS + c) * 2 + 1) * DIM + d];
  }
  float cnt = (float)(cums[seg + 1] - cums[seg]);
  float mean = s / fmaxf(cnt, 1.f);
  float var = (ss - cnt * mean * mean) / fmaxf(cnt - 1.f, 1.f);
  gm[seg * DIM + d] = mean;
  gi[seg * DIM + d] = 1.f / (sqrtf(fmaxf(var, 0.f)) + 1e-5f);
}

__global__ __launch_bounds__(256) void gn_apply_kernel(
    const float* __restrict__ X, const float* __restrict__ gamma,
    const float* __restrict__ betag, const int* __restrict__ cums, int nseg,
    const float* __restrict__ gm, const float* __restrict__ gi,
    float* __restrict__ Xout, float* __restrict__ ofinal) {
  int idx = blockIdx.x * 256 + threadIdx.x;
  int base = idx * 4;
  int row = base >> 8, d0 = base & 255;
  int seg = 0;
  for (int b = 1; b <= nseg; ++b) seg += (row >= cums[b]) ? 1 : 0;
  float4 x = ((const float4*)X)[idx];
  float xs[4] = {x.x, x.y, x.z, x.w};
  const float* gmp = gm + seg * DIM + d0;
  const float* gip = gi + seg * DIM + d0;
  float o[4];
#pragma unroll
  for (int c = 0; c < 4; ++c)
    o[c] = gamma[d0 + c] * (xs[c] - gmp[c]) * gip[c] + betag[d0 + c];
  float4 ov = {o[0], o[1], o[2], o[3]};
  ((float4*)Xout)[idx] = ov;
  if (ofinal) ((float4*)ofinal)[idx] = ov;
}

// ---------------------------------------------------------------------------
extern "C" void kernel_launch(void* const* d_in, const int* in_sizes, int n_in,
                              void* d_out, int out_size, void* d_ws,
                              size_t ws_size, hipStream_t stream) {
  const float* xyz0 = (const float*)d_in[0];
  const float* x0 = (const float*)d_in[1];
  const float* yhat = (const float*)d_in[2];
  const int* dmask = (const int*)d_in[3];
  const int* tptr = (const int*)d_in[4];
  const float* bwp = (const float*)d_in[5];
  const float* betap = (const float*)d_in[6];
  const int* cums = (const int*)d_in[7];
  const int* bmask = (const int*)d_in[8];
  const int* usestdp = (const int*)d_in[9];
  const int* selfdp = (const int*)d_in[10];
  const float* qw = (const float*)d_in[11];
  const float* kw = (const float*)d_in[12];
  const float* vw = (const float*)d_in[13];
  const float* ow = (const float*)d_in[14];
  const float* qbv = (const float*)d_in[15];
  const float* kbv = (const float*)d_in[16];
  const float* vbv = (const float*)d_in[17];
  const float* obv = (const float*)d_in[18];
  const float* gamma = (const float*)d_in[19];
  const float* betag = (const float*)d_in[20];
  float* out = (float*)d_out;
  float* ws = (float*)d_ws;

  const size_t ND = (size_t)N_ROWS * DIM;  // 1,048,576 words

  // ---- region A [0, 4*ND words): Vb16 (qkv out) -> bt (QM out) -> plo
  us* Vb16 = (us*)ws;
  float* bt = ws;
  us* plo = (us*)ws;
  // ---- region B: all pointers CHAINED
  us* Qh = (us*)(ws + 4 * ND);                 // 4096*288 us
  us* Kh = Qh + (size_t)N_ROWS * LDQ;          // 4096*288 us
  us* Vtb = Kh + (size_t)N_ROWS * LDQ;         // 272*4096 us
  unsigned int* mbits = (unsigned int*)(Vtb + (size_t)272 * N_ROWS);
  float* kpart = (float*)(mbits + (size_t)N_ROWS * 128);
  float* ksum = kpart + 64 * DIM;
  float* c1a = ksum + DIM;
  float* cAa = c1a + N_ROWS;
  float* colB = cAa + N_ROWS;
  float* logy = colB + N_ROWS;
  float* xyzA = logy + N_ROWS;
  float* xyzB = xyzA + 3 * N_ROWS;
  float* gm = xyzB + 3 * N_ROWS;
  float* gi = gm + 8 * DIM;
  float* gpart = gi + 8 * DIM;
  float* psbase = gpart + 8 * GN_CHUNKS * 2 * DIM;
  float* paxlo = psbase + 16 * (size_t)N_ROWS;
  float* paxhi = paxlo + 8 * (size_t)N_ROWS * 3;
  us* Mb16 = (us*)(paxhi + 8 * (size_t)N_ROWS * 3);
  float* Pend = (float*)(Mb16 + 65536);  // P0
  // ---- overlay region [P0 ...): {bo, Ktb, Mp} XOR {phi}
  float* bo = Pend;                                  // ND f32
  us* Ktb = (us*)(bo + ND);                          // 256*4096 us
  float* Mp = (float*)(Ktb + (size_t)256 * N_ROWS);  // 8*65536 f32
  us* phi = (us*)Pend;                               // 8 splits * ND us
  us* xattb = Ktb;                                   // merge out (post-flash)
  const size_t P0w = (size_t)(Pend - ws);
  const size_t full16 = (P0w + 5 * ND) * 4;
  const int nsplit = (ws_size >= full16) ? 16 : 8;
  const int cps = N_ROWS / nsplit;
  float* bx = Pend + (size_t)(nsplit == 16 ? 4 : 2) * ND;  // layer out f32

  const int nseg = in_sizes[7] - 1;

  prep_kernel<<<16, 256, 0, stream>>>(yhat, logy);
  maskpack_kernel<<<65536, 256, 0, stream>>>(dmask, bmask, mbits);

  for (int l = 0; l < NLAYER; ++l) {
    const float* xin = (l == 0) ? x0 : bx;
    const float* xyz_in = (l == 0) ? xyz0 : ((l & 1) ? xyzB : xyzA);
    float* xyz_o = (l & 1) ? xyzA : xyzB;
    const size_t wo = (size_t)l * DIM * DIM;

    mfma_qkv_kernel<<<dim3(64, 4, 3), 256, 0, stream>>>(
        xin, qw + wo, kw + wo, vw + wo, qbv + l * DIM, kbv + l * DIM,
        vbv + l * DIM, Qh, Kh, Vb16);
    ksum_part_kernel<<<64, 256, 0, stream>>>(Kh, kpart);
    vt2_kernel<<<dim3(64, 4, 2), 256, 0, stream>>>(Kh, Vb16, Ktb, Vtb);
    ksum_red_kernel<<<1, 256, 0, stream>>>(kpart, ksum);
    mpart_mfma_kernel<<<dim3(4, 4, 8), 256, 0, stream>>>(Ktb, Mp);
    mreduce_kernel<<<256, 256, 0, stream>>>(Mp, Mb16);
    mfma_nt_kernel<<<dim3(64, 4), 256, 0, stream>>>(Qh, LDQ, Mb16, nullptr,
                                                    nullptr, nullptr, bt);
    stats_kernel<<<1024, 256, 0, stream>>>(Qh, Kh, Vtb, bt, ksum, xyz_in, logy,
                                           tptr, bwp, usestdp, c1a, cAa, colB);
    flash5_kernel<<<dim3(nsplit, 32), 256, 0, stream>>>(
        Qh, Kh, Vtb, colB, c1a, cAa, mbits, bwp, selfdp, plo, phi, psbase,
        paxlo, paxhi, cps);
    merge_kernel<<<1024, 256, 0, stream>>>(plo, phi, psbase, paxlo, paxhi,
                                           xyz_in, betap, xattb, xyz_o,
                                           nsplit);
    mfma_nt_kernel<<<dim3(64, 4), 256, 0, stream>>>(
        xattb, DIM, nullptr, ow + wo, obv + l * DIM, xin, bo);
    gn_part_kernel<<<dim3(nseg, GN_CHUNKS), 256, 0, stream>>>(bo, cums, gpart);
    gn_red_kernel<<<nseg, 256, 0, stream>>>(gpart, cums, gm, gi);
    gn_apply_kernel<<<1024, 256, 0, stream>>>(
        bo, gamma + (size_t)l * DIM, betag + (size_t)l * DIM, cums, nseg, gm,
        gi, bx, (l == NLAYER - 1) ? out : nullptr);
  }
}

// Round 12
// 725.158 us; speedup vs baseline: 1.2918x; 1.2918x over previous
//
#include <hip/hip_runtime.h>
#include <hip/hip_bf16.h>
#include <math.h>

#define N_ROWS 4096
#define DIM    256
#define LDQ    288
#define NLAYER 4
#define GN_CHUNKS 16

typedef __attribute__((ext_vector_type(8))) short bf16x8;
typedef __attribute__((ext_vector_type(4))) float f32x4;
typedef unsigned short us;

__device__ __forceinline__ us f2b(float f) {
  unsigned int u = __float_as_uint(f);
  unsigned int r = (u + 0x7fffu + ((u >> 16) & 1u)) >> 16;
  return (us)r;
}
__device__ __forceinline__ float b2f(us b) {
  return __uint_as_float(((unsigned int)b) << 16);
}
__device__ __forceinline__ bf16x8 f8_to_b8(float4 a, float4 b) {
  bf16x8 r;
  r[0] = (short)f2b(a.x);
  r[1] = (short)f2b(a.y);
  r[2] = (short)f2b(a.z);
  r[3] = (short)f2b(a.w);
  r[4] = (short)f2b(b.x);
  r[5] = (short)f2b(b.y);
  r[6] = (short)f2b(b.z);
  r[7] = (short)f2b(b.w);
  return r;
}
// async global -> LDS, 16B per lane (dest = wave-uniform base + lane*16)
__device__ __forceinline__ void gload16(const us* g, short* l) {
  __builtin_amdgcn_global_load_lds(
      (const __attribute__((address_space(1))) unsigned int*)g,
      (__attribute__((address_space(3))) unsigned int*)l, 16, 0, 0);
}

// ---------------------------------------------------------------------------
// MFMA NT GEMM: C[M,256](f32) = A(bf16,lda) @ B^T (+bias)(+res)
// B either bf16 (Bb) or f32 (Bf) — exactly one non-null.
// ---------------------------------------------------------------------------
__global__ __launch_bounds__(256) void mfma_nt_kernel(
    const us* __restrict__ A, int lda, const us* __restrict__ Bb,
    const float* __restrict__ Bf, const float* __restrict__ bias,
    const float* __restrict__ res, float* __restrict__ C) {
  __shared__ __align__(16) short Al[64 * 32];
  __shared__ __align__(16) short Bl[64 * 32];
  const int tid = threadIdx.x;
  const int wv = tid >> 6, lane = tid & 63;
  const int cl = lane & 15, gq = lane >> 4;
  const int wr = wv >> 1, wc = wv & 1;
  const int m0 = blockIdx.x * 64, n0 = blockIdx.y * 64;
  f32x4 acc[2][2];
#pragma unroll
  for (int mi = 0; mi < 2; ++mi)
#pragma unroll
    for (int ni = 0; ni < 2; ++ni) acc[mi][ni] = (f32x4){0.f, 0.f, 0.f, 0.f};
  for (int k0 = 0; k0 < DIM; k0 += 32) {
    __syncthreads();
    {
      int r = tid >> 2, c = tid & 3;
      *(bf16x8*)&Al[r * 32 + c * 8] =
          *(const bf16x8*)&A[(size_t)(m0 + r) * lda + k0 + c * 8];
      if (Bf) {
        float4 u = *(const float4*)&Bf[(size_t)(n0 + r) * DIM + k0 + c * 8];
        float4 v =
            *(const float4*)&Bf[(size_t)(n0 + r) * DIM + k0 + c * 8 + 4];
        *(bf16x8*)&Bl[r * 32 + c * 8] = f8_to_b8(u, v);
      } else {
        *(bf16x8*)&Bl[r * 32 + c * 8] =
            *(const bf16x8*)&Bb[(size_t)(n0 + r) * DIM + k0 + c * 8];
      }
    }
    __syncthreads();
    bf16x8 af[2], bfr[2];
#pragma unroll
    for (int mi = 0; mi < 2; ++mi)
      af[mi] = *(const bf16x8*)&Al[(wr * 32 + mi * 16 + cl) * 32 + gq * 8];
#pragma unroll
    for (int ni = 0; ni < 2; ++ni)
      bfr[ni] = *(const bf16x8*)&Bl[(wc * 32 + ni * 16 + cl) * 32 + gq * 8];
#pragma unroll
    for (int mi = 0; mi < 2; ++mi)
#pragma unroll
      for (int ni = 0; ni < 2; ++ni)
        acc[mi][ni] = __builtin_amdgcn_mfma_f32_16x16x32_bf16(
            af[mi], bfr[ni], acc[mi][ni], 0, 0, 0);
  }
#pragma unroll
  for (int mi = 0; mi < 2; ++mi)
#pragma unroll
    for (int ni = 0; ni < 2; ++ni)
#pragma unroll
      for (int i = 0; i < 4; ++i) {
        int row = m0 + wr * 32 + mi * 16 + gq * 4 + i;
        int col = n0 + wc * 32 + ni * 16 + cl;
        float v = acc[mi][ni][i];
        if (bias) v += bias[col];
        if (res) v += res[(size_t)row * DIM + col];
        C[(size_t)row * DIM + col] = v;
      }
}

// ---------------------------------------------------------------------------
// Fused QKV MFMA: A f32, W f32 (converted in staging); bf16 outputs
// ---------------------------------------------------------------------------
__global__ __launch_bounds__(256) void mfma_qkv_kernel(
    const float* __restrict__ A, const float* __restrict__ W0,
    const float* __restrict__ W1, const float* __restrict__ W2,
    const float* __restrict__ b0, const float* __restrict__ b1,
    const float* __restrict__ b2, us* __restrict__ O0, us* __restrict__ O1,
    us* __restrict__ O2) {
  const float* Bm = (blockIdx.z == 0) ? W0 : (blockIdx.z == 1) ? W1 : W2;
  const float* bias = (blockIdx.z == 0) ? b0 : (blockIdx.z == 1) ? b1 : b2;
  us* Ob = (blockIdx.z == 0) ? O0 : (blockIdx.z == 1) ? O1 : O2;
  const int ldo = (blockIdx.z == 2) ? DIM : LDQ;
  __shared__ __align__(16) short Al[64 * 32];
  __shared__ __align__(16) short Bl[64 * 32];
  const int tid = threadIdx.x;
  const int wv = tid >> 6, lane = tid & 63;
  const int cl = lane & 15, gq = lane >> 4;
  const int wr = wv >> 1, wc = wv & 1;
  const int m0 = blockIdx.x * 64, n0 = blockIdx.y * 64;
  f32x4 acc[2][2];
#pragma unroll
  for (int mi = 0; mi < 2; ++mi)
#pragma unroll
    for (int ni = 0; ni < 2; ++ni) acc[mi][ni] = (f32x4){0.f, 0.f, 0.f, 0.f};
  for (int k0 = 0; k0 < DIM; k0 += 32) {
    __syncthreads();
    {
      int r = tid >> 2, c = tid & 3;
      float4 ua = *(const float4*)&A[(size_t)(m0 + r) * DIM + k0 + c * 8];
      float4 va = *(const float4*)&A[(size_t)(m0 + r) * DIM + k0 + c * 8 + 4];
      *(bf16x8*)&Al[r * 32 + c * 8] = f8_to_b8(ua, va);
      float4 ub = *(const float4*)&Bm[(size_t)(n0 + r) * DIM + k0 + c * 8];
      float4 vb = *(const float4*)&Bm[(size_t)(n0 + r) * DIM + k0 + c * 8 + 4];
      *(bf16x8*)&Bl[r * 32 + c * 8] = f8_to_b8(ub, vb);
    }
    __syncthreads();
    bf16x8 af[2], bfr[2];
#pragma unroll
    for (int mi = 0; mi < 2; ++mi)
      af[mi] = *(const bf16x8*)&Al[(wr * 32 + mi * 16 + cl) * 32 + gq * 8];
#pragma unroll
    for (int ni = 0; ni < 2; ++ni)
      bfr[ni] = *(const bf16x8*)&Bl[(wc * 32 + ni * 16 + cl) * 32 + gq * 8];
#pragma unroll
    for (int mi = 0; mi < 2; ++mi)
#pragma unroll
      for (int ni = 0; ni < 2; ++ni)
        acc[mi][ni] = __builtin_amdgcn_mfma_f32_16x16x32_bf16(
            af[mi], bfr[ni], acc[mi][ni], 0, 0, 0);
  }
#pragma unroll
  for (int mi = 0; mi < 2; ++mi)
#pragma unroll
    for (int ni = 0; ni < 2; ++ni)
#pragma unroll
      for (int i = 0; i < 4; ++i) {
        int row = m0 + wr * 32 + mi * 16 + gq * 4 + i;
        int col = n0 + wc * 32 + ni * 16 + cl;
        Ob[(size_t)row * ldo + col] = f2b(acc[mi][ni][i] + bias[col]);
      }
}

// ---------------------------------------------------------------------------
// Mpart[z] = Kt[:, z*512:+512] @ same^T (Kt bf16 [256][4096])
// ---------------------------------------------------------------------------
__global__ __launch_bounds__(256) void mpart_mfma_kernel(
    const us* __restrict__ Kt, float* __restrict__ Mp) {
  __shared__ __align__(16) short Al[64 * 32];
  __shared__ __align__(16) short Bl[64 * 32];
  const int tid = threadIdx.x;
  const int wv = tid >> 6, lane = tid & 63;
  const int cl = lane & 15, gq = lane >> 4;
  const int wr = wv >> 1, wc = wv & 1;
  const int a0 = blockIdx.x * 64, b0 = blockIdx.y * 64;
  const int kb = blockIdx.z * 512;
  f32x4 acc[2][2];
#pragma unroll
  for (int mi = 0; mi < 2; ++mi)
#pragma unroll
    for (int ni = 0; ni < 2; ++ni) acc[mi][ni] = (f32x4){0.f, 0.f, 0.f, 0.f};
  for (int k0 = 0; k0 < 512; k0 += 32) {
    __syncthreads();
    {
      int r = tid >> 2, c = tid & 3;
      *(bf16x8*)&Al[r * 32 + c * 8] =
          *(const bf16x8*)&Kt[(size_t)(a0 + r) * N_ROWS + kb + k0 + c * 8];
      *(bf16x8*)&Bl[r * 32 + c * 8] =
          *(const bf16x8*)&Kt[(size_t)(b0 + r) * N_ROWS + kb + k0 + c * 8];
    }
    __syncthreads();
    bf16x8 af[2], bfr[2];
#pragma unroll
    for (int mi = 0; mi < 2; ++mi)
      af[mi] = *(const bf16x8*)&Al[(wr * 32 + mi * 16 + cl) * 32 + gq * 8];
#pragma unroll
    for (int ni = 0; ni < 2; ++ni)
      bfr[ni] = *(const bf16x8*)&Bl[(wc * 32 + ni * 16 + cl) * 32 + gq * 8];
#pragma unroll
    for (int mi = 0; mi < 2; ++mi)
#pragma unroll
      for (int ni = 0; ni < 2; ++ni)
        acc[mi][ni] = __builtin_amdgcn_mfma_f32_16x16x32_bf16(
            af[mi], bfr[ni], acc[mi][ni], 0, 0, 0);
  }
#pragma unroll
  for (int mi = 0; mi < 2; ++mi)
#pragma unroll
    for (int ni = 0; ni < 2; ++ni)
#pragma unroll
      for (int i = 0; i < 4; ++i) {
        int row = a0 + wr * 32 + mi * 16 + gq * 4 + i;
        int col = b0 + wc * 32 + ni * 16 + cl;
        Mp[(size_t)blockIdx.z * 65536 + (size_t)row * DIM + col] =
            acc[mi][ni][i];
      }
}

__global__ void mreduce_kernel(const float* __restrict__ Mp,
                               us* __restrict__ Mb) {
  int e = blockIdx.x * 256 + threadIdx.x;
  float s = 0.f;
#pragma unroll
  for (int z = 0; z < 8; ++z) s += Mp[(size_t)z * 65536 + e];
  Mb[e] = f2b(s);
}

// ---------------------------------------------------------------------------
__global__ void ksum_part_kernel(const us* __restrict__ K,
                                 float* __restrict__ kpart) {
  int d = threadIdx.x, b = blockIdx.x;
  float s = 0.f;
  int base = b * 64;
  for (int n = 0; n < 64; ++n) s += b2f(K[(size_t)(base + n) * LDQ + d]);
  kpart[b * DIM + d] = s;
}
__global__ void ksum_red_kernel(const float* __restrict__ kpart,
                                float* __restrict__ ksum) {
  int d = threadIdx.x;
  float s = 0.f;
  for (int b = 0; b < 64; ++b) s += kpart[b * DIM + d];
  ksum[d] = s;
}

// ---------------------------------------------------------------------------
// stats: per-row mean/istd -> c1,cA; writes Qhat/Khat tails, Vhat tail rows,
// colB. grid 1024 x 256 (wave per row)
// ---------------------------------------------------------------------------
__global__ __launch_bounds__(256) void stats_kernel(
    us* __restrict__ Qh, us* __restrict__ Kh, us* __restrict__ Vtb,
    const float* __restrict__ tb, const float* __restrict__ ksum,
    const float* __restrict__ xyzc, const float* __restrict__ logy,
    const int* __restrict__ tptr, const float* __restrict__ bwp,
    const int* __restrict__ usestdp, float* __restrict__ c1a,
    float* __restrict__ cAa, float* __restrict__ colB) {
  const int wave = threadIdx.x >> 6, lane = threadIdx.x & 63;
  const int row = blockIdx.x * 4 + wave;
  ushort4 q4 = *(const ushort4*)&Qh[(size_t)row * LDQ + lane * 4];
  float qx = b2f(q4.x), qy = b2f(q4.y), qz = b2f(q4.z), qw = b2f(q4.w);
  const float4 tv4 = ((const float4*)(tb + (size_t)row * DIM))[lane];
  const float4 kv = ((const float4*)ksum)[lane];
  float p1 = qx * kv.x + qy * kv.y + qz * kv.z + qw * kv.w;
  float p2 = tv4.x * qx + tv4.y * qy + tv4.z * qz + tv4.w * qw;
#pragma unroll
  for (int off = 32; off >= 1; off >>= 1) {
    p1 += __shfl_xor(p1, off);
    p2 += __shfl_xor(p2, off);
  }
  float tt = (float)tptr[0];
  float sc = 1.f / (16.f * tt);
  float mean = p1 * sc * (1.f / (float)N_ROWS);
  float e2 = p2 * sc * sc * (1.f / (float)N_ROWS);
  float var = fmaxf(e2 - mean * mean, 0.f);
  float istd = 1.f / (sqrtf(var) + 1e-5f);
  int usestd = usestdp[0];
  float c1 = usestd ? sc * istd : sc;
  float c2 = usestd ? -mean * istd : 0.f;
  float bw = bwp[0];
  float i2 = 1.f / (2.f * bw * bw);
  float t2 = 2.f * i2;
  float x0 = xyzc[(size_t)row * 3 + 0];
  float x1 = xyzc[(size_t)row * 3 + 1];
  float x2 = xyzc[(size_t)row * 3 + 2];
  float sq = x0 * x0 + x1 * x1 + x2 * x2;
  if (lane == 0) {
    c1a[row] = c1;
    cAa[row] = c2 - sq * i2;
    colB[row] = logy[row] - sq * i2;
  }
  float qs = t2 / c1;
  if (lane < 32) {
    float v = (lane == 0) ? qs * x0
              : (lane == 1) ? qs * x1
              : (lane == 2) ? qs * x2
                            : 0.f;
    Qh[(size_t)row * LDQ + 256 + lane] = (lane < 3) ? f2b(v) : 0;
  } else {
    int j = lane - 32;
    float v = (j == 0) ? x0 : (j == 1) ? x1 : (j == 2) ? x2 : 0.f;
    Kh[(size_t)row * LDQ + 256 + j] = (j < 3) ? f2b(v) : 0;
  }
  if (lane < 16) {
    us v = 0;
    if (lane == 0) v = f2b(x0);
    else if (lane == 1) v = f2b(x1);
    else if (lane == 2) v = f2b(x2);
    else if (lane == 3) v = 0x3F80;  // 1.0
    Vtb[(size_t)(256 + lane) * N_ROWS + row] = v;
  }
}

__global__ void prep_kernel(const float* __restrict__ yhat,
                            float* __restrict__ logy) {
  int i = blockIdx.x * 256 + threadIdx.x;
  logy[i] = logf(yhat[i] + 1e-9f);
}

__global__ void maskpack_kernel(const int* __restrict__ dmask,
                                const int* __restrict__ bmask,
                                unsigned int* __restrict__ mbits) {
  int gid = blockIdx.x * 256 + threadIdx.x;
  bool v = (dmask[gid] != 0) && (bmask[gid] != 0);
  unsigned long long bal = __ballot(v);
  if ((threadIdx.x & 63) == 0) {
    int w = gid >> 5;
    mbits[w] = (unsigned int)(bal & 0xffffffffu);
    mbits[w + 1] = (unsigned int)(bal >> 32);
  }
}

// ---------------------------------------------------------------------------
// Transpose bf16 [4096, lda] (cols 0..255) -> bf16 [256][4096]
// ---------------------------------------------------------------------------
__global__ __launch_bounds__(256) void vt2_kernel(const us* __restrict__ inK,
                                                  const us* __restrict__ inV,
                                                  us* __restrict__ outK,
                                                  us* __restrict__ outV) {
  __shared__ us T[64][68];
  const us* in = (blockIdx.z == 0) ? inK : inV;
  us* out = (blockIdx.z == 0) ? outK : outV;
  const int lda = (blockIdx.z == 0) ? LDQ : DIM;
  const int n0 = blockIdx.x * 64, d0 = blockIdx.y * 64;
  const int tx = threadIdx.x & 63, ty = threadIdx.x >> 6;
#pragma unroll
  for (int p = 0; p < 16; ++p)
    T[ty + p * 4][tx] = in[(size_t)(n0 + ty + p * 4) * lda + d0 + tx];
  __syncthreads();
#pragma unroll
  for (int p = 0; p < 16; ++p)
    out[(size_t)(d0 + ty + p * 4) * N_ROWS + n0 + tx] = T[tx][ty + p * 4];
}

// ---------------------------------------------------------------------------
// Flash v7: 32 q-rows/wave, augmented operands; XCD-aware grid;
// DOUBLE-BUFFERED async global_load_lds staging (zero staging registers);
// coalesced partial writes via LDS re-assembly.
// grid (nsplit, 32), block 256 (4 waves).
// ---------------------------------------------------------------------------
__global__ __launch_bounds__(256, 2) void flash5_kernel(
    const us* __restrict__ Qh, const us* __restrict__ Kh,
    const us* __restrict__ Vtb, const float* __restrict__ colB,
    const float* __restrict__ c1a, const float* __restrict__ cAa,
    const unsigned int* __restrict__ mbits, const float* __restrict__ bwp,
    const int* __restrict__ selfdp, us* __restrict__ plo, us* __restrict__ phi,
    float* __restrict__ ps, float* __restrict__ paxlo,
    float* __restrict__ paxhi, int cps) {
  // 2 x (Kh 1152 + Vh 1088 chunks)*16B + P 8KB = 79872 B (2 blocks/CU)
  __shared__ __align__(16) short SMEM[39936];
  short* Pl = SMEM + 35840;  // 8*512 shorts

  const int tid = threadIdx.x;
  const int wv = tid >> 6, lane = tid & 63;
  const int cl = lane & 15, gq = lane >> 4;
  const int split = blockIdx.x;  // XCD = (y*nsplit+split)%8 = split%8
  const int R0 = blockIdx.y * 128 + wv * 32;
  const int colbase = split * cps;

  const float bw = bwp[0];
  const float i2 = 1.f / (2.f * bw * bw);
  const float sd2 = (float)selfdp[0] * i2;

  bf16x8 qa[2][9];
#pragma unroll
  for (int rt = 0; rt < 2; ++rt) {
    const bf16x8* qp = (const bf16x8*)(Qh + (size_t)(R0 + rt * 16 + cl) * LDQ);
#pragma unroll
    for (int ks = 0; ks < 9; ++ks) qa[rt][ks] = qp[ks * 4 + gq];
  }
  float c1v[2][4], cAv[2][4];
#pragma unroll
  for (int rt = 0; rt < 2; ++rt)
#pragma unroll
    for (int i = 0; i < 4; ++i) {
      int row = R0 + rt * 16 + gq * 4 + i;
      c1v[rt][i] = c1a[row];
      cAv[rt][i] = cAa[row];
    }
  f32x4 o[2][17];
#pragma unroll
  for (int rt = 0; rt < 2; ++rt)
#pragma unroll
    for (int dt = 0; dt < 17; ++dt) o[rt][dt] = (f32x4){0.f, 0.f, 0.f, 0.f};

  // async stage tile at t0g into buffer b (no registers held)
  auto stage = [&](int t0g, int b) {
    short* base = SMEM + b * 17920;
#pragma unroll
    for (int p = 0; p < 9; ++p) {
      int L = tid + p * 256;
      if (L < 1152) {  // wave-uniform (1152 = 18*64)
        int ks = L >> 7, ct = (L >> 6) & 1, g = (L >> 4) & 3, c = L & 15;
        gload16(&Kh[(size_t)(t0g + 2 * c + ct) * LDQ + ks * 32 + g * 8],
                &base[L * 8]);
      } else if (L < 2240) {  // wave-uniform (2240 = 35*64)
        int L2 = L - 1152;
        int dt2 = L2 >> 6, g = (L2 >> 4) & 3, c = L2 & 15;
        gload16(&Vtb[(size_t)(dt2 * 16 + c) * N_ROWS + t0g + g * 8],
                &base[9216 + L2 * 8]);
      }
    }
  };

  stage(colbase, 0);
  __syncthreads();  // drains vmcnt: tile 0 ready
  int cur = 0;

  for (int tt = 0; tt < cps; tt += 32) {
    const int t0g = colbase + tt;
    if (tt + 32 < cps) stage(t0g + 32, cur ^ 1);  // overlaps compute below
    const short* Khl = SMEM + cur * 17920;
    const short* Vhl = Khl + 9216;

    const int gc0 = t0g + 2 * cl;
    const float cb0 = colB[gc0];
    const float cb1 = colB[gc0 + 1];

#pragma unroll
    for (int rt = 0; rt < 2; ++rt) {
      f32x4 s0 = (f32x4){0.f, 0.f, 0.f, 0.f};
      f32x4 s1 = (f32x4){0.f, 0.f, 0.f, 0.f};
#pragma unroll
      for (int ks = 0; ks < 9; ++ks) {
        bf16x8 kf = *(const bf16x8*)&Khl[(ks * 128 + gq * 16 + cl) * 8];
        s0 = __builtin_amdgcn_mfma_f32_16x16x32_bf16(qa[rt][ks], kf, s0, 0, 0,
                                                     0);
      }
#pragma unroll
      for (int ks = 0; ks < 9; ++ks) {
        bf16x8 kf = *(const bf16x8*)&Khl[(ks * 128 + 64 + gq * 16 + cl) * 8];
        s1 = __builtin_amdgcn_mfma_f32_16x16x32_bf16(qa[rt][ks], kf, s1, 0, 0,
                                                     0);
      }
#pragma unroll
      for (int i = 0; i < 4; ++i) {
        int row = R0 + rt * 16 + gq * 4 + i;
        unsigned int mw = mbits[((size_t)row << 7) + (t0g >> 5)];
        unsigned int pm = (mw >> (2 * cl)) & 3u;
        float lg0 = fmaf(s0[i], c1v[rt][i], cAv[rt][i] + cb0);
        float lg1 = fmaf(s1[i], c1v[rt][i], cAv[rt][i] + cb1);
        if (row == gc0) lg0 -= sd2;
        if (row == gc0 + 1) lg1 -= sd2;
        lg0 = (pm & 1u) ? lg0 : -60.f;
        lg1 = (pm & 2u) ? lg1 : -60.f;
        float p0 = __expf(lg0);
        float p1 = __expf(lg1);
        unsigned int pk =
            (unsigned int)f2b(p0) | ((unsigned int)f2b(p1) << 16);
        *(unsigned int*)&Pl[(wv * 2 + rt) * 512 +
                            ((cl >> 2) * 16 + gq * 4 + i) * 8 + (cl & 3) * 2] =
            pk;
      }
    }
    bf16x8 pf0 = *(const bf16x8*)&Pl[(wv * 2 + 0) * 512 + (gq * 16 + cl) * 8];
    bf16x8 pf1 = *(const bf16x8*)&Pl[(wv * 2 + 1) * 512 + (gq * 16 + cl) * 8];
#pragma unroll
    for (int dt = 0; dt < 17; ++dt) {
      bf16x8 vf = *(const bf16x8*)&Vhl[(dt * 64 + gq * 16 + cl) * 8];
      o[0][dt] = __builtin_amdgcn_mfma_f32_16x16x32_bf16(pf0, vf, o[0][dt], 0,
                                                         0, 0);
      o[1][dt] = __builtin_amdgcn_mfma_f32_16x16x32_bf16(pf1, vf, o[1][dt], 0,
                                                         0, 0);
    }
    __syncthreads();  // drains vmcnt (next tile ready) + LDS reads done
    cur ^= 1;
  }

  // epilogue: assemble o row-major in LDS, write coalesced 512B rows
  us* pb = (split < 8) ? plo : phi;
  float* paxb = (split < 8) ? paxlo : paxhi;
  const int sl = split & 7;
  short* obuf = SMEM + wv * 4096;  // 8 KB per wave (buffers are dead)
#pragma unroll
  for (int rt = 0; rt < 2; ++rt) {
#pragma unroll
    for (int dt = 0; dt < 16; ++dt)
#pragma unroll
      for (int i = 0; i < 4; ++i)
        obuf[(gq * 4 + i) * 256 + dt * 16 + cl] = (short)f2b(o[rt][dt][i]);
    // same-wave LDS ordering: reads below wait on writes above (lgkmcnt)
#pragma unroll
    for (int p = 0; p < 8; ++p) {
      int idx = p * 512 + lane * 8;
      int rl = idx >> 8;
      int col = idx & 255;
      bf16x8 v = *(const bf16x8*)&obuf[idx];
      *(bf16x8*)&pb[((size_t)sl * N_ROWS + R0 + rt * 16 + rl) * DIM + col] = v;
    }
#pragma unroll
    for (int i = 0; i < 4; ++i) {
      int row = R0 + rt * 16 + gq * 4 + i;
      float aug = o[rt][16][i];
      if (cl < 3)
        paxb[((size_t)sl * N_ROWS + row) * 3 + cl] = aug;
      else if (cl == 3)
        ps[(size_t)split * N_ROWS + row] = aug;
    }
  }
}

// ---------------------------------------------------------------------------
// Merge nsplit raw partials: O = (sum o_k)/(sum s_k); xyz update
// ---------------------------------------------------------------------------
__global__ __launch_bounds__(256) void merge_kernel(
    const us* __restrict__ plo, const us* __restrict__ phi,
    const float* __restrict__ ps, const float* __restrict__ paxlo,
    const float* __restrict__ paxhi, const float* __restrict__ xyzc,
    const float* __restrict__ betap, us* __restrict__ xattb,
    float* __restrict__ xyz_out, int nsplit) {
  const int wvl = threadIdx.x >> 6, lane = threadIdx.x & 63;
  const int row = blockIdx.x * 4 + wvl;
  float den = 0.f;
  for (int k = 0; k < nsplit; ++k) den += ps[(size_t)k * N_ROWS + row];
  float inv = 1.f / den;
  float a0 = 0.f, a1 = 0.f, a2 = 0.f, a3 = 0.f;
  float axs = 0.f;
  for (int k = 0; k < nsplit; ++k) {
    const us* pb = (k < 8) ? plo : phi;
    const us* p = &pb[((size_t)(k & 7) * N_ROWS + row) * DIM + lane * 4];
    uint2 u = *(const uint2*)p;
    a0 += __uint_as_float((u.x & 0xffffu) << 16);
    a1 += __uint_as_float(u.x & 0xffff0000u);
    a2 += __uint_as_float((u.y & 0xffffu) << 16);
    a3 += __uint_as_float(u.y & 0xffff0000u);
    if (lane < 3) {
      const float* paxb = (k < 8) ? paxlo : paxhi;
      axs += paxb[((size_t)(k & 7) * N_ROWS + row) * 3 + lane];
    }
  }
  ushort4 ov;
  ov.x = f2b(a0 * inv);
  ov.y = f2b(a1 * inv);
  ov.z = f2b(a2 * inv);
  ov.w = f2b(a3 * inv);
  *(ushort4*)&xattb[(size_t)row * DIM + lane * 4] = ov;
  if (lane < 3) {
    float beta = betap[0];
    xyz_out[(size_t)row * 3 + lane] =
        beta * axs * inv + (1.f - beta) * xyzc[(size_t)row * 3 + lane];
  }
}

// ---------------------------------------------------------------------------
// GraphNorm
// ---------------------------------------------------------------------------
__global__ __launch_bounds__(256) void gn_part_kernel(
    const float* __restrict__ X, const int* __restrict__ cums,
    float* __restrict__ gpart) {
  const int seg = blockIdx.x, chunk = blockIdx.y, d = threadIdx.x;
  const int r0 = cums[seg], r1 = cums[seg + 1];
  const int cnt = r1 - r0;
  const int per = (cnt + GN_CHUNKS - 1) / GN_CHUNKS;
  const int a = r0 + chunk * per;
  const int b = min(a + per, r1);
  float s = 0.f, ss = 0.f;
  for (int r = a; r < b; ++r) {
    float v = X[(size_t)r * DIM + d];
    s += v;
    ss += v * v;
  }
  gpart[(((size_t)seg * GN_CHUNKS + chunk) * 2 + 0) * DIM + d] = s;
  gpart[(((size_t)seg * GN_CHUNKS + chunk) * 2 + 1) * DIM + d] = ss;
}

__global__ void gn_red_kernel(const float* __restrict__ gpart,
                              const int* __restrict__ cums,
                              float* __restrict__ gm, float* __restrict__ gi) {
  const int seg = blockIdx.x, d = threadIdx.x;
  float s = 0.f, ss = 0.f;
#pragma unroll
  for (int c = 0; c < GN_CHUNKS; ++c) {
    s += gpart[(((size_t)seg * GN_CHUNKS + c) * 2 + 0) * DIM + d];
    ss += gpart[(((size_t)seg * GN_CHUNKS + c) * 2 + 1) * DIM + d];
  }
  float cnt = (float)(cums[seg + 1] - cums[seg]);
  float mean = s / fmaxf(cnt, 1.f);
  float var = (ss - cnt * mean * mean) / fmaxf(cnt - 1.f, 1.f);
  gm[seg * DIM + d] = mean;
  gi[seg * DIM + d] = 1.f / (sqrtf(fmaxf(var, 0.f)) + 1e-5f);
}

__global__ __launch_bounds__(256) void gn_apply_kernel(
    const float* __restrict__ X, const float* __restrict__ gamma,
    const float* __restrict__ betag, const int* __restrict__ cums, int nseg,
    const float* __restrict__ gm, const float* __restrict__ gi,
    float* __restrict__ Xout, float* __restrict__ ofinal) {
  int idx = blockIdx.x * 256 + threadIdx.x;
  int base = idx * 4;
  int row = base >> 8, d0 = base & 255;
  int seg = 0;
  for (int b = 1; b <= nseg; ++b) seg += (row >= cums[b]) ? 1 : 0;
  float4 x = ((const float4*)X)[idx];
  float xs[4] = {x.x, x.y, x.z, x.w};
  const float* gmp = gm + seg * DIM + d0;
  const float* gip = gi + seg * DIM + d0;
  float o[4];
#pragma unroll
  for (int c = 0; c < 4; ++c)
    o[c] = gamma[d0 + c] * (xs[c] - gmp[c]) * gip[c] + betag[d0 + c];
  float4 ov = {o[0], o[1], o[2], o[3]};
  ((float4*)Xout)[idx] = ov;
  if (ofinal) ((float4*)ofinal)[idx] = ov;
}

// ---------------------------------------------------------------------------
extern "C" void kernel_launch(void* const* d_in, const int* in_sizes, int n_in,
                              void* d_out, int out_size, void* d_ws,
                              size_t ws_size, hipStream_t stream) {
  const float* xyz0 = (const float*)d_in[0];
  const float* x0 = (const float*)d_in[1];
  const float* yhat = (const float*)d_in[2];
  const int* dmask = (const int*)d_in[3];
  const int* tptr = (const int*)d_in[4];
  const float* bwp = (const float*)d_in[5];
  const float* betap = (const float*)d_in[6];
  const int* cums = (const int*)d_in[7];
  const int* bmask = (const int*)d_in[8];
  const int* usestdp = (const int*)d_in[9];
  const int* selfdp = (const int*)d_in[10];
  const float* qw = (const float*)d_in[11];
  const float* kw = (const float*)d_in[12];
  const float* vw = (const float*)d_in[13];
  const float* ow = (const float*)d_in[14];
  const float* qbv = (const float*)d_in[15];
  const float* kbv = (const float*)d_in[16];
  const float* vbv = (const float*)d_in[17];
  const float* obv = (const float*)d_in[18];
  const float* gamma = (const float*)d_in[19];
  const float* betag = (const float*)d_in[20];
  float* out = (float*)d_out;
  float* ws = (float*)d_ws;

  const size_t ND = (size_t)N_ROWS * DIM;  // 1,048,576 words

  // ---- region A [0, 4*ND words): Vb16 (qkv out) -> bt (QM out) -> plo
  us* Vb16 = (us*)ws;
  float* bt = ws;
  us* plo = (us*)ws;
  // ---- region B: all pointers CHAINED
  us* Qh = (us*)(ws + 4 * ND);                 // 4096*288 us
  us* Kh = Qh + (size_t)N_ROWS * LDQ;          // 4096*288 us
  us* Vtb = Kh + (size_t)N_ROWS * LDQ;         // 272*4096 us
  unsigned int* mbits = (unsigned int*)(Vtb + (size_t)272 * N_ROWS);
  float* kpart = (float*)(mbits + (size_t)N_ROWS * 128);
  float* ksum = kpart + 64 * DIM;
  float* c1a = ksum + DIM;
  float* cAa = c1a + N_ROWS;
  float* colB = cAa + N_ROWS;
  float* logy = colB + N_ROWS;
  float* xyzA = logy + N_ROWS;
  float* xyzB = xyzA + 3 * N_ROWS;
  float* gm = xyzB + 3 * N_ROWS;
  float* gi = gm + 8 * DIM;
  float* gpart = gi + 8 * DIM;
  float* psbase = gpart + 8 * GN_CHUNKS * 2 * DIM;
  float* paxlo = psbase + 16 * (size_t)N_ROWS;
  float* paxhi = paxlo + 8 * (size_t)N_ROWS * 3;
  us* Mb16 = (us*)(paxhi + 8 * (size_t)N_ROWS * 3);
  float* Pend = (float*)(Mb16 + 65536);  // P0
  // ---- overlay region [P0 ...): {bo, Ktb, Mp} XOR {phi}
  float* bo = Pend;                                  // ND f32
  us* Ktb = (us*)(bo + ND);                          // 256*4096 us
  float* Mp = (float*)(Ktb + (size_t)256 * N_ROWS);  // 8*65536 f32
  us* phi = (us*)Pend;                               // 8 splits * ND us
  us* xattb = Ktb;                                   // merge out (post-flash)
  const size_t P0w = (size_t)(Pend - ws);
  const size_t full16 = (P0w + 5 * ND) * 4;
  const int nsplit = (ws_size >= full16) ? 16 : 8;
  const int cps = N_ROWS / nsplit;
  float* bx = Pend + (size_t)(nsplit == 16 ? 4 : 2) * ND;  // layer out f32

  const int nseg = in_sizes[7] - 1;

  prep_kernel<<<16, 256, 0, stream>>>(yhat, logy);
  maskpack_kernel<<<65536, 256, 0, stream>>>(dmask, bmask, mbits);

  for (int l = 0; l < NLAYER; ++l) {
    const float* xin = (l == 0) ? x0 : bx;
    const float* xyz_in = (l == 0) ? xyz0 : ((l & 1) ? xyzB : xyzA);
    float* xyz_o = (l & 1) ? xyzA : xyzB;
    const size_t wo = (size_t)l * DIM * DIM;

    mfma_qkv_kernel<<<dim3(64, 4, 3), 256, 0, stream>>>(
        xin, qw + wo, kw + wo, vw + wo, qbv + l * DIM, kbv + l * DIM,
        vbv + l * DIM, Qh, Kh, Vb16);
    ksum_part_kernel<<<64, 256, 0, stream>>>(Kh, kpart);
    vt2_kernel<<<dim3(64, 4, 2), 256, 0, stream>>>(Kh, Vb16, Ktb, Vtb);
    ksum_red_kernel<<<1, 256, 0, stream>>>(kpart, ksum);
    mpart_mfma_kernel<<<dim3(4, 4, 8), 256, 0, stream>>>(Ktb, Mp);
    mreduce_kernel<<<256, 256, 0, stream>>>(Mp, Mb16);
    mfma_nt_kernel<<<dim3(64, 4), 256, 0, stream>>>(Qh, LDQ, Mb16, nullptr,
                                                    nullptr, nullptr, bt);
    stats_kernel<<<1024, 256, 0, stream>>>(Qh, Kh, Vtb, bt, ksum, xyz_in, logy,
                                           tptr, bwp, usestdp, c1a, cAa, colB);
    flash5_kernel<<<dim3(nsplit, 32), 256, 0, stream>>>(
        Qh, Kh, Vtb, colB, c1a, cAa, mbits, bwp, selfdp, plo, phi, psbase,
        paxlo, paxhi, cps);
    merge_kernel<<<1024, 256, 0, stream>>>(plo, phi, psbase, paxlo, paxhi,
                                           xyz_in, betap, xattb, xyz_o,
                                           nsplit);
    mfma_nt_kernel<<<dim3(64, 4), 256, 0, stream>>>(
        xattb, DIM, nullptr, ow + wo, obv + l * DIM, xin, bo);
    gn_part_kernel<<<dim3(nseg, GN_CHUNKS), 256, 0, stream>>>(bo, cums, gpart);
    gn_red_kernel<<<nseg, 256, 0, stream>>>(gpart, cums, gm, gi);
    gn_apply_kernel<<<1024, 256, 0, stream>>>(
        bo, gamma + (size_t)l * DIM, betag + (size_t)l * DIM, cums, nseg, gm,
        gi, bx, (l == NLAYER - 1) ? out : nullptr);
  }
}

// Round 13
// 720.971 us; speedup vs baseline: 1.2993x; 1.0058x over previous
//
#include <hip/hip_runtime.h>
#include <hip/hip_bf16.h>
#include <math.h>

#define N_ROWS 4096
#define DIM    256
#define LDQ    288
#define NLAYER 4
#define GN_CHUNKS 16

typedef __attribute__((ext_vector_type(8))) short bf16x8;
typedef __attribute__((ext_vector_type(4))) float f32x4;
typedef unsigned short us;

__device__ __forceinline__ us f2b(float f) {
  unsigned int u = __float_as_uint(f);
  unsigned int r = (u + 0x7fffu + ((u >> 16) & 1u)) >> 16;
  return (us)r;
}
__device__ __forceinline__ float b2f(us b) {
  return __uint_as_float(((unsigned int)b) << 16);
}
__device__ __forceinline__ bf16x8 f8_to_b8(float4 a, float4 b) {
  bf16x8 r;
  r[0] = (short)f2b(a.x);
  r[1] = (short)f2b(a.y);
  r[2] = (short)f2b(a.z);
  r[3] = (short)f2b(a.w);
  r[4] = (short)f2b(b.x);
  r[5] = (short)f2b(b.y);
  r[6] = (short)f2b(b.z);
  r[7] = (short)f2b(b.w);
  return r;
}
// async global -> LDS, 16B per lane (dest = wave-uniform base + lane*16)
__device__ __forceinline__ void gload16(const us* g, short* l) {
  __builtin_amdgcn_global_load_lds(
      (const __attribute__((address_space(1))) unsigned int*)g,
      (__attribute__((address_space(3))) unsigned int*)l, 16, 0, 0);
}

// ---------------------------------------------------------------------------
// MFMA NT GEMM: C[M,256](f32) = A(bf16,lda) @ B^T (+bias)(+res)
// B either bf16 (Bb) or f32 (Bf) — exactly one non-null.
// ---------------------------------------------------------------------------
__global__ __launch_bounds__(256) void mfma_nt_kernel(
    const us* __restrict__ A, int lda, const us* __restrict__ Bb,
    const float* __restrict__ Bf, const float* __restrict__ bias,
    const float* __restrict__ res, float* __restrict__ C) {
  __shared__ __align__(16) short Al[64 * 32];
  __shared__ __align__(16) short Bl[64 * 32];
  const int tid = threadIdx.x;
  const int wv = tid >> 6, lane = tid & 63;
  const int cl = lane & 15, gq = lane >> 4;
  const int wr = wv >> 1, wc = wv & 1;
  const int m0 = blockIdx.x * 64, n0 = blockIdx.y * 64;
  f32x4 acc[2][2];
#pragma unroll
  for (int mi = 0; mi < 2; ++mi)
#pragma unroll
    for (int ni = 0; ni < 2; ++ni) acc[mi][ni] = (f32x4){0.f, 0.f, 0.f, 0.f};
  for (int k0 = 0; k0 < DIM; k0 += 32) {
    __syncthreads();
    {
      int r = tid >> 2, c = tid & 3;
      *(bf16x8*)&Al[r * 32 + c * 8] =
          *(const bf16x8*)&A[(size_t)(m0 + r) * lda + k0 + c * 8];
      if (Bf) {
        float4 u = *(const float4*)&Bf[(size_t)(n0 + r) * DIM + k0 + c * 8];
        float4 v =
            *(const float4*)&Bf[(size_t)(n0 + r) * DIM + k0 + c * 8 + 4];
        *(bf16x8*)&Bl[r * 32 + c * 8] = f8_to_b8(u, v);
      } else {
        *(bf16x8*)&Bl[r * 32 + c * 8] =
            *(const bf16x8*)&Bb[(size_t)(n0 + r) * DIM + k0 + c * 8];
      }
    }
    __syncthreads();
    bf16x8 af[2], bfr[2];
#pragma unroll
    for (int mi = 0; mi < 2; ++mi)
      af[mi] = *(const bf16x8*)&Al[(wr * 32 + mi * 16 + cl) * 32 + gq * 8];
#pragma unroll
    for (int ni = 0; ni < 2; ++ni)
      bfr[ni] = *(const bf16x8*)&Bl[(wc * 32 + ni * 16 + cl) * 32 + gq * 8];
#pragma unroll
    for (int mi = 0; mi < 2; ++mi)
#pragma unroll
      for (int ni = 0; ni < 2; ++ni)
        acc[mi][ni] = __builtin_amdgcn_mfma_f32_16x16x32_bf16(
            af[mi], bfr[ni], acc[mi][ni], 0, 0, 0);
  }
#pragma unroll
  for (int mi = 0; mi < 2; ++mi)
#pragma unroll
    for (int ni = 0; ni < 2; ++ni)
#pragma unroll
      for (int i = 0; i < 4; ++i) {
        int row = m0 + wr * 32 + mi * 16 + gq * 4 + i;
        int col = n0 + wc * 32 + ni * 16 + cl;
        float v = acc[mi][ni][i];
        if (bias) v += bias[col];
        if (res) v += res[(size_t)row * DIM + col];
        C[(size_t)row * DIM + col] = v;
      }
}

// ---------------------------------------------------------------------------
// Fused QKV MFMA: A f32, W f32 (converted in staging); bf16 outputs
// ---------------------------------------------------------------------------
__global__ __launch_bounds__(256) void mfma_qkv_kernel(
    const float* __restrict__ A, const float* __restrict__ W0,
    const float* __restrict__ W1, const float* __restrict__ W2,
    const float* __restrict__ b0, const float* __restrict__ b1,
    const float* __restrict__ b2, us* __restrict__ O0, us* __restrict__ O1,
    us* __restrict__ O2) {
  const float* Bm = (blockIdx.z == 0) ? W0 : (blockIdx.z == 1) ? W1 : W2;
  const float* bias = (blockIdx.z == 0) ? b0 : (blockIdx.z == 1) ? b1 : b2;
  us* Ob = (blockIdx.z == 0) ? O0 : (blockIdx.z == 1) ? O1 : O2;
  const int ldo = (blockIdx.z == 2) ? DIM : LDQ;
  __shared__ __align__(16) short Al[64 * 32];
  __shared__ __align__(16) short Bl[64 * 32];
  const int tid = threadIdx.x;
  const int wv = tid >> 6, lane = tid & 63;
  const int cl = lane & 15, gq = lane >> 4;
  const int wr = wv >> 1, wc = wv & 1;
  const int m0 = blockIdx.x * 64, n0 = blockIdx.y * 64;
  f32x4 acc[2][2];
#pragma unroll
  for (int mi = 0; mi < 2; ++mi)
#pragma unroll
    for (int ni = 0; ni < 2; ++ni) acc[mi][ni] = (f32x4){0.f, 0.f, 0.f, 0.f};
  for (int k0 = 0; k0 < DIM; k0 += 32) {
    __syncthreads();
    {
      int r = tid >> 2, c = tid & 3;
      float4 ua = *(const float4*)&A[(size_t)(m0 + r) * DIM + k0 + c * 8];
      float4 va = *(const float4*)&A[(size_t)(m0 + r) * DIM + k0 + c * 8 + 4];
      *(bf16x8*)&Al[r * 32 + c * 8] = f8_to_b8(ua, va);
      float4 ub = *(const float4*)&Bm[(size_t)(n0 + r) * DIM + k0 + c * 8];
      float4 vb = *(const float4*)&Bm[(size_t)(n0 + r) * DIM + k0 + c * 8 + 4];
      *(bf16x8*)&Bl[r * 32 + c * 8] = f8_to_b8(ub, vb);
    }
    __syncthreads();
    bf16x8 af[2], bfr[2];
#pragma unroll
    for (int mi = 0; mi < 2; ++mi)
      af[mi] = *(const bf16x8*)&Al[(wr * 32 + mi * 16 + cl) * 32 + gq * 8];
#pragma unroll
    for (int ni = 0; ni < 2; ++ni)
      bfr[ni] = *(const bf16x8*)&Bl[(wc * 32 + ni * 16 + cl) * 32 + gq * 8];
#pragma unroll
    for (int mi = 0; mi < 2; ++mi)
#pragma unroll
      for (int ni = 0; ni < 2; ++ni)
        acc[mi][ni] = __builtin_amdgcn_mfma_f32_16x16x32_bf16(
            af[mi], bfr[ni], acc[mi][ni], 0, 0, 0);
  }
#pragma unroll
  for (int mi = 0; mi < 2; ++mi)
#pragma unroll
    for (int ni = 0; ni < 2; ++ni)
#pragma unroll
      for (int i = 0; i < 4; ++i) {
        int row = m0 + wr * 32 + mi * 16 + gq * 4 + i;
        int col = n0 + wc * 32 + ni * 16 + cl;
        Ob[(size_t)row * ldo + col] = f2b(acc[mi][ni][i] + bias[col]);
      }
}

// ---------------------------------------------------------------------------
// Mpart[z] = Kt[:, z*512:+512] @ same^T (Kt bf16 [256][4096])
// ---------------------------------------------------------------------------
__global__ __launch_bounds__(256) void mpart_mfma_kernel(
    const us* __restrict__ Kt, float* __restrict__ Mp) {
  __shared__ __align__(16) short Al[64 * 32];
  __shared__ __align__(16) short Bl[64 * 32];
  const int tid = threadIdx.x;
  const int wv = tid >> 6, lane = tid & 63;
  const int cl = lane & 15, gq = lane >> 4;
  const int wr = wv >> 1, wc = wv & 1;
  const int a0 = blockIdx.x * 64, b0 = blockIdx.y * 64;
  const int kb = blockIdx.z * 512;
  f32x4 acc[2][2];
#pragma unroll
  for (int mi = 0; mi < 2; ++mi)
#pragma unroll
    for (int ni = 0; ni < 2; ++ni) acc[mi][ni] = (f32x4){0.f, 0.f, 0.f, 0.f};
  for (int k0 = 0; k0 < 512; k0 += 32) {
    __syncthreads();
    {
      int r = tid >> 2, c = tid & 3;
      *(bf16x8*)&Al[r * 32 + c * 8] =
          *(const bf16x8*)&Kt[(size_t)(a0 + r) * N_ROWS + kb + k0 + c * 8];
      *(bf16x8*)&Bl[r * 32 + c * 8] =
          *(const bf16x8*)&Kt[(size_t)(b0 + r) * N_ROWS + kb + k0 + c * 8];
    }
    __syncthreads();
    bf16x8 af[2], bfr[2];
#pragma unroll
    for (int mi = 0; mi < 2; ++mi)
      af[mi] = *(const bf16x8*)&Al[(wr * 32 + mi * 16 + cl) * 32 + gq * 8];
#pragma unroll
    for (int ni = 0; ni < 2; ++ni)
      bfr[ni] = *(const bf16x8*)&Bl[(wc * 32 + ni * 16 + cl) * 32 + gq * 8];
#pragma unroll
    for (int mi = 0; mi < 2; ++mi)
#pragma unroll
      for (int ni = 0; ni < 2; ++ni)
        acc[mi][ni] = __builtin_amdgcn_mfma_f32_16x16x32_bf16(
            af[mi], bfr[ni], acc[mi][ni], 0, 0, 0);
  }
#pragma unroll
  for (int mi = 0; mi < 2; ++mi)
#pragma unroll
    for (int ni = 0; ni < 2; ++ni)
#pragma unroll
      for (int i = 0; i < 4; ++i) {
        int row = a0 + wr * 32 + mi * 16 + gq * 4 + i;
        int col = b0 + wc * 32 + ni * 16 + cl;
        Mp[(size_t)blockIdx.z * 65536 + (size_t)row * DIM + col] =
            acc[mi][ni][i];
      }
}

__global__ void mreduce_kernel(const float* __restrict__ Mp,
                               us* __restrict__ Mb) {
  int e = blockIdx.x * 256 + threadIdx.x;
  float s = 0.f;
#pragma unroll
  for (int z = 0; z < 8; ++z) s += Mp[(size_t)z * 65536 + e];
  Mb[e] = f2b(s);
}

// ---------------------------------------------------------------------------
__global__ void ksum_part_kernel(const us* __restrict__ K,
                                 float* __restrict__ kpart) {
  int d = threadIdx.x, b = blockIdx.x;
  float s = 0.f;
  int base = b * 64;
  for (int n = 0; n < 64; ++n) s += b2f(K[(size_t)(base + n) * LDQ + d]);
  kpart[b * DIM + d] = s;
}
__global__ void ksum_red_kernel(const float* __restrict__ kpart,
                                float* __restrict__ ksum) {
  int d = threadIdx.x;
  float s = 0.f;
  for (int b = 0; b < 64; ++b) s += kpart[b * DIM + d];
  ksum[d] = s;
}

// ---------------------------------------------------------------------------
// stats: per-row mean/istd -> c1,cA; writes Qhat/Khat tails, Vhat tail rows,
// colB. grid 1024 x 256 (wave per row)
// ---------------------------------------------------------------------------
__global__ __launch_bounds__(256) void stats_kernel(
    us* __restrict__ Qh, us* __restrict__ Kh, us* __restrict__ Vtb,
    const float* __restrict__ tb, const float* __restrict__ ksum,
    const float* __restrict__ xyzc, const float* __restrict__ logy,
    const int* __restrict__ tptr, const float* __restrict__ bwp,
    const int* __restrict__ usestdp, float* __restrict__ c1a,
    float* __restrict__ cAa, float* __restrict__ colB) {
  const int wave = threadIdx.x >> 6, lane = threadIdx.x & 63;
  const int row = blockIdx.x * 4 + wave;
  ushort4 q4 = *(const ushort4*)&Qh[(size_t)row * LDQ + lane * 4];
  float qx = b2f(q4.x), qy = b2f(q4.y), qz = b2f(q4.z), qw = b2f(q4.w);
  const float4 tv4 = ((const float4*)(tb + (size_t)row * DIM))[lane];
  const float4 kv = ((const float4*)ksum)[lane];
  float p1 = qx * kv.x + qy * kv.y + qz * kv.z + qw * kv.w;
  float p2 = tv4.x * qx + tv4.y * qy + tv4.z * qz + tv4.w * qw;
#pragma unroll
  for (int off = 32; off >= 1; off >>= 1) {
    p1 += __shfl_xor(p1, off);
    p2 += __shfl_xor(p2, off);
  }
  float tt = (float)tptr[0];
  float sc = 1.f / (16.f * tt);
  float mean = p1 * sc * (1.f / (float)N_ROWS);
  float e2 = p2 * sc * sc * (1.f / (float)N_ROWS);
  float var = fmaxf(e2 - mean * mean, 0.f);
  float istd = 1.f / (sqrtf(var) + 1e-5f);
  int usestd = usestdp[0];
  float c1 = usestd ? sc * istd : sc;
  float c2 = usestd ? -mean * istd : 0.f;
  float bw = bwp[0];
  float i2 = 1.f / (2.f * bw * bw);
  float t2 = 2.f * i2;
  float x0 = xyzc[(size_t)row * 3 + 0];
  float x1 = xyzc[(size_t)row * 3 + 1];
  float x2 = xyzc[(size_t)row * 3 + 2];
  float sq = x0 * x0 + x1 * x1 + x2 * x2;
  if (lane == 0) {
    c1a[row] = c1;
    cAa[row] = c2 - sq * i2;
    colB[row] = logy[row] - sq * i2;
  }
  float qs = t2 / c1;
  if (lane < 32) {
    float v = (lane == 0) ? qs * x0
              : (lane == 1) ? qs * x1
              : (lane == 2) ? qs * x2
                            : 0.f;
    Qh[(size_t)row * LDQ + 256 + lane] = (lane < 3) ? f2b(v) : 0;
  } else {
    int j = lane - 32;
    float v = (j == 0) ? x0 : (j == 1) ? x1 : (j == 2) ? x2 : 0.f;
    Kh[(size_t)row * LDQ + 256 + j] = (j < 3) ? f2b(v) : 0;
  }
  if (lane < 16) {
    us v = 0;
    if (lane == 0) v = f2b(x0);
    else if (lane == 1) v = f2b(x1);
    else if (lane == 2) v = f2b(x2);
    else if (lane == 3) v = 0x3F80;  // 1.0
    Vtb[(size_t)(256 + lane) * N_ROWS + row] = v;
  }
}

__global__ void prep_kernel(const float* __restrict__ yhat,
                            float* __restrict__ logy) {
  int i = blockIdx.x * 256 + threadIdx.x;
  logy[i] = logf(yhat[i] + 1e-9f);
}

__global__ void maskpack_kernel(const int* __restrict__ dmask,
                                const int* __restrict__ bmask,
                                unsigned int* __restrict__ mbits) {
  int gid = blockIdx.x * 256 + threadIdx.x;
  bool v = (dmask[gid] != 0) && (bmask[gid] != 0);
  unsigned long long bal = __ballot(v);
  if ((threadIdx.x & 63) == 0) {
    int w = gid >> 5;
    mbits[w] = (unsigned int)(bal & 0xffffffffu);
    mbits[w + 1] = (unsigned int)(bal >> 32);
  }
}

// ---------------------------------------------------------------------------
// Transpose bf16 [4096, lda] (cols 0..255) -> bf16 [256][4096]
// ---------------------------------------------------------------------------
__global__ __launch_bounds__(256) void vt2_kernel(const us* __restrict__ inK,
                                                  const us* __restrict__ inV,
                                                  us* __restrict__ outK,
                                                  us* __restrict__ outV) {
  __shared__ us T[64][68];
  const us* in = (blockIdx.z == 0) ? inK : inV;
  us* out = (blockIdx.z == 0) ? outK : outV;
  const int lda = (blockIdx.z == 0) ? LDQ : DIM;
  const int n0 = blockIdx.x * 64, d0 = blockIdx.y * 64;
  const int tx = threadIdx.x & 63, ty = threadIdx.x >> 6;
#pragma unroll
  for (int p = 0; p < 16; ++p)
    T[ty + p * 4][tx] = in[(size_t)(n0 + ty + p * 4) * lda + d0 + tx];
  __syncthreads();
#pragma unroll
  for (int p = 0; p < 16; ++p)
    out[(size_t)(d0 + ty + p * 4) * N_ROWS + n0 + tx] = T[tx][ty + p * 4];
}

// ---------------------------------------------------------------------------
// Flash v8: 32 q-rows/wave; XCD-aware grid; K-hat double-buffered via
// async global_load_lds; V-hat read DIRECTLY from global (L2-resident per
// XCD — no LDS staging). LDS 45 KB -> 3 blocks/CU.
// grid (nsplit, 32), block 256 (4 waves).
// ---------------------------------------------------------------------------
__global__ __launch_bounds__(256, 2) void flash5_kernel(
    const us* __restrict__ Qh, const us* __restrict__ Kh,
    const us* __restrict__ Vtb, const float* __restrict__ colB,
    const float* __restrict__ c1a, const float* __restrict__ cAa,
    const unsigned int* __restrict__ mbits, const float* __restrict__ bwp,
    const int* __restrict__ selfdp, us* __restrict__ plo, us* __restrict__ phi,
    float* __restrict__ ps, float* __restrict__ paxlo,
    float* __restrict__ paxhi, int cps) {
  // 2 x Khat(1152 chunks x 16B) + P 8KB = 45056 B -> 3 blocks/CU
  __shared__ __align__(16) short SMEM[22528];
  short* Pl = SMEM + 18432;  // 8*512 shorts

  const int tid = threadIdx.x;
  const int wv = tid >> 6, lane = tid & 63;
  const int cl = lane & 15, gq = lane >> 4;
  const int split = blockIdx.x;  // XCD = (y*nsplit+split)%8 = split%8
  const int R0 = blockIdx.y * 128 + wv * 32;
  const int colbase = split * cps;

  const float bw = bwp[0];
  const float i2 = 1.f / (2.f * bw * bw);
  const float sd2 = (float)selfdp[0] * i2;

  bf16x8 qa[2][9];
#pragma unroll
  for (int rt = 0; rt < 2; ++rt) {
    const bf16x8* qp = (const bf16x8*)(Qh + (size_t)(R0 + rt * 16 + cl) * LDQ);
#pragma unroll
    for (int ks = 0; ks < 9; ++ks) qa[rt][ks] = qp[ks * 4 + gq];
  }
  float c1v[2][4], cAv[2][4];
#pragma unroll
  for (int rt = 0; rt < 2; ++rt)
#pragma unroll
    for (int i = 0; i < 4; ++i) {
      int row = R0 + rt * 16 + gq * 4 + i;
      c1v[rt][i] = c1a[row];
      cAv[rt][i] = cAa[row];
    }
  f32x4 o[2][17];
#pragma unroll
  for (int rt = 0; rt < 2; ++rt)
#pragma unroll
    for (int dt = 0; dt < 17; ++dt) o[rt][dt] = (f32x4){0.f, 0.f, 0.f, 0.f};

  // async stage K-hat tile at t0g into buffer b (no registers held)
  auto stage = [&](int t0g, int b) {
    short* base = SMEM + b * 9216;
#pragma unroll
    for (int p = 0; p < 5; ++p) {
      int L = tid + p * 256;
      if (L < 1152) {  // wave-uniform (1152 = 18*64)
        int ks = L >> 7, ct = (L >> 6) & 1, g = (L >> 4) & 3, c = L & 15;
        gload16(&Kh[(size_t)(t0g + 2 * c + ct) * LDQ + ks * 32 + g * 8],
                &base[L * 8]);
      }
    }
  };

  stage(colbase, 0);
  __syncthreads();  // drains vmcnt: tile 0 ready
  int cur = 0;

  for (int tt = 0; tt < cps; tt += 32) {
    const int t0g = colbase + tt;
    if (tt + 32 < cps) stage(t0g + 32, cur ^ 1);  // overlaps compute below
    const short* Khl = SMEM + cur * 9216;

    const int gc0 = t0g + 2 * cl;
    const float cb0 = colB[gc0];
    const float cb1 = colB[gc0 + 1];

#pragma unroll
    for (int rt = 0; rt < 2; ++rt) {
      f32x4 s0 = (f32x4){0.f, 0.f, 0.f, 0.f};
      f32x4 s1 = (f32x4){0.f, 0.f, 0.f, 0.f};
#pragma unroll
      for (int ks = 0; ks < 9; ++ks) {
        bf16x8 kf = *(const bf16x8*)&Khl[(ks * 128 + gq * 16 + cl) * 8];
        s0 = __builtin_amdgcn_mfma_f32_16x16x32_bf16(qa[rt][ks], kf, s0, 0, 0,
                                                     0);
      }
#pragma unroll
      for (int ks = 0; ks < 9; ++ks) {
        bf16x8 kf = *(const bf16x8*)&Khl[(ks * 128 + 64 + gq * 16 + cl) * 8];
        s1 = __builtin_amdgcn_mfma_f32_16x16x32_bf16(qa[rt][ks], kf, s1, 0, 0,
                                                     0);
      }
#pragma unroll
      for (int i = 0; i < 4; ++i) {
        int row = R0 + rt * 16 + gq * 4 + i;
        unsigned int mw = mbits[((size_t)row << 7) + (t0g >> 5)];
        unsigned int pm = (mw >> (2 * cl)) & 3u;
        float lg0 = fmaf(s0[i], c1v[rt][i], cAv[rt][i] + cb0);
        float lg1 = fmaf(s1[i], c1v[rt][i], cAv[rt][i] + cb1);
        if (row == gc0) lg0 -= sd2;
        if (row == gc0 + 1) lg1 -= sd2;
        lg0 = (pm & 1u) ? lg0 : -60.f;
        lg1 = (pm & 2u) ? lg1 : -60.f;
        float p0 = __expf(lg0);
        float p1 = __expf(lg1);
        unsigned int pk =
            (unsigned int)f2b(p0) | ((unsigned int)f2b(p1) << 16);
        *(unsigned int*)&Pl[(wv * 2 + rt) * 512 +
                            ((cl >> 2) * 16 + gq * 4 + i) * 8 + (cl & 3) * 2] =
            pk;
      }
    }
    bf16x8 pf0 = *(const bf16x8*)&Pl[(wv * 2 + 0) * 512 + (gq * 16 + cl) * 8];
    bf16x8 pf1 = *(const bf16x8*)&Pl[(wv * 2 + 1) * 512 + (gq * 16 + cl) * 8];
#pragma unroll
    for (int dt = 0; dt < 17; ++dt) {
      // V-hat fragment straight from global (L2-resident on this XCD)
      bf16x8 vf =
          *(const bf16x8*)&Vtb[(size_t)(dt * 16 + cl) * N_ROWS + t0g + gq * 8];
      o[0][dt] = __builtin_amdgcn_mfma_f32_16x16x32_bf16(pf0, vf, o[0][dt], 0,
                                                         0, 0);
      o[1][dt] = __builtin_amdgcn_mfma_f32_16x16x32_bf16(pf1, vf, o[1][dt], 0,
                                                         0, 0);
    }
    __syncthreads();  // drains vmcnt (next K tile ready) + LDS reads done
    cur ^= 1;
  }

  // epilogue: assemble o row-major in LDS, write coalesced 512B rows
  us* pb = (split < 8) ? plo : phi;
  float* paxb = (split < 8) ? paxlo : paxhi;
  const int sl = split & 7;
  short* obuf = SMEM + wv * 4096;  // 8 KB per wave (buffers are dead)
#pragma unroll
  for (int rt = 0; rt < 2; ++rt) {
#pragma unroll
    for (int dt = 0; dt < 16; ++dt)
#pragma unroll
      for (int i = 0; i < 4; ++i)
        obuf[(gq * 4 + i) * 256 + dt * 16 + cl] = (short)f2b(o[rt][dt][i]);
    // same-wave LDS ordering: reads below wait on writes above (lgkmcnt)
#pragma unroll
    for (int p = 0; p < 8; ++p) {
      int idx = p * 512 + lane * 8;
      int rl = idx >> 8;
      int col = idx & 255;
      bf16x8 v = *(const bf16x8*)&obuf[idx];
      *(bf16x8*)&pb[((size_t)sl * N_ROWS + R0 + rt * 16 + rl) * DIM + col] = v;
    }
#pragma unroll
    for (int i = 0; i < 4; ++i) {
      int row = R0 + rt * 16 + gq * 4 + i;
      float aug = o[rt][16][i];
      if (cl < 3)
        paxb[((size_t)sl * N_ROWS + row) * 3 + cl] = aug;
      else if (cl == 3)
        ps[(size_t)split * N_ROWS + row] = aug;
    }
  }
}

// ---------------------------------------------------------------------------
// Merge nsplit raw partials: O = (sum o_k)/(sum s_k); xyz update
// ---------------------------------------------------------------------------
__global__ __launch_bounds__(256) void merge_kernel(
    const us* __restrict__ plo, const us* __restrict__ phi,
    const float* __restrict__ ps, const float* __restrict__ paxlo,
    const float* __restrict__ paxhi, const float* __restrict__ xyzc,
    const float* __restrict__ betap, us* __restrict__ xattb,
    float* __restrict__ xyz_out, int nsplit) {
  const int wvl = threadIdx.x >> 6, lane = threadIdx.x & 63;
  const int row = blockIdx.x * 4 + wvl;
  float den = 0.f;
  for (int k = 0; k < nsplit; ++k) den += ps[(size_t)k * N_ROWS + row];
  float inv = 1.f / den;
  float a0 = 0.f, a1 = 0.f, a2 = 0.f, a3 = 0.f;
  float axs = 0.f;
  for (int k = 0; k < nsplit; ++k) {
    const us* pb = (k < 8) ? plo : phi;
    const us* p = &pb[((size_t)(k & 7) * N_ROWS + row) * DIM + lane * 4];
    uint2 u = *(const uint2*)p;
    a0 += __uint_as_float((u.x & 0xffffu) << 16);
    a1 += __uint_as_float(u.x & 0xffff0000u);
    a2 += __uint_as_float((u.y & 0xffffu) << 16);
    a3 += __uint_as_float(u.y & 0xffff0000u);
    if (lane < 3) {
      const float* paxb = (k < 8) ? paxlo : paxhi;
      axs += paxb[((size_t)(k & 7) * N_ROWS + row) * 3 + lane];
    }
  }
  ushort4 ov;
  ov.x = f2b(a0 * inv);
  ov.y = f2b(a1 * inv);
  ov.z = f2b(a2 * inv);
  ov.w = f2b(a3 * inv);
  *(ushort4*)&xattb[(size_t)row * DIM + lane * 4] = ov;
  if (lane < 3) {
    float beta = betap[0];
    xyz_out[(size_t)row * 3 + lane] =
        beta * axs * inv + (1.f - beta) * xyzc[(size_t)row * 3 + lane];
  }
}

// ---------------------------------------------------------------------------
// GraphNorm
// ---------------------------------------------------------------------------
__global__ __launch_bounds__(256) void gn_part_kernel(
    const float* __restrict__ X, const int* __restrict__ cums,
    float* __restrict__ gpart) {
  const int seg = blockIdx.x, chunk = blockIdx.y, d = threadIdx.x;
  const int r0 = cums[seg], r1 = cums[seg + 1];
  const int cnt = r1 - r0;
  const int per = (cnt + GN_CHUNKS - 1) / GN_CHUNKS;
  const int a = r0 + chunk * per;
  const int b = min(a + per, r1);
  float s = 0.f, ss = 0.f;
  for (int r = a; r < b; ++r) {
    float v = X[(size_t)r * DIM + d];
    s += v;
    ss += v * v;
  }
  gpart[(((size_t)seg * GN_CHUNKS + chunk) * 2 + 0) * DIM + d] = s;
  gpart[(((size_t)seg * GN_CHUNKS + chunk) * 2 + 1) * DIM + d] = ss;
}

__global__ void gn_red_kernel(const float* __restrict__ gpart,
                              const int* __restrict__ cums,
                              float* __restrict__ gm, float* __restrict__ gi) {
  const int seg = blockIdx.x, d = threadIdx.x;
  float s = 0.f, ss = 0.f;
#pragma unroll
  for (int c = 0; c < GN_CHUNKS; ++c) {
    s += gpart[(((size_t)seg * GN_CHUNKS + c) * 2 + 0) * DIM + d];
    ss += gpart[(((size_t)seg * GN_CHUNKS + c) * 2 + 1) * DIM + d];
  }
  float cnt = (float)(cums[seg + 1] - cums[seg]);
  float mean = s / fmaxf(cnt, 1.f);
  float var = (ss - cnt * mean * mean) / fmaxf(cnt - 1.f, 1.f);
  gm[seg * DIM + d] = mean;
  gi[seg * DIM + d] = 1.f / (sqrtf(fmaxf(var, 0.f)) + 1e-5f);
}

__global__ __launch_bounds__(256) void gn_apply_kernel(
    const float* __restrict__ X, const float* __restrict__ gamma,
    const float* __restrict__ betag, const int* __restrict__ cums, int nseg,
    const float* __restrict__ gm, const float* __restrict__ gi,
    float* __restrict__ Xout, float* __restrict__ ofinal) {
  int idx = blockIdx.x * 256 + threadIdx.x;
  int base = idx * 4;
  int row = base >> 8, d0 = base & 255;
  int seg = 0;
  for (int b = 1; b <= nseg; ++b) seg += (row >= cums[b]) ? 1 : 0;
  float4 x = ((const float4*)X)[idx];
  float xs[4] = {x.x, x.y, x.z, x.w};
  const float* gmp = gm + seg * DIM + d0;
  const float* gip = gi + seg * DIM + d0;
  float o[4];
#pragma unroll
  for (int c = 0; c < 4; ++c)
    o[c] = gamma[d0 + c] * (xs[c] - gmp[c]) * gip[c] + betag[d0 + c];
  float4 ov = {o[0], o[1], o[2], o[3]};
  ((float4*)Xout)[idx] = ov;
  if (ofinal) ((float4*)ofinal)[idx] = ov;
}

// ---------------------------------------------------------------------------
extern "C" void kernel_launch(void* const* d_in, const int* in_sizes, int n_in,
                              void* d_out, int out_size, void* d_ws,
                              size_t ws_size, hipStream_t stream) {
  const float* xyz0 = (const float*)d_in[0];
  const float* x0 = (const float*)d_in[1];
  const float* yhat = (const float*)d_in[2];
  const int* dmask = (const int*)d_in[3];
  const int* tptr = (const int*)d_in[4];
  const float* bwp = (const float*)d_in[5];
  const float* betap = (const float*)d_in[6];
  const int* cums = (const int*)d_in[7];
  const int* bmask = (const int*)d_in[8];
  const int* usestdp = (const int*)d_in[9];
  const int* selfdp = (const int*)d_in[10];
  const float* qw = (const float*)d_in[11];
  const float* kw = (const float*)d_in[12];
  const float* vw = (const float*)d_in[13];
  const float* ow = (const float*)d_in[14];
  const float* qbv = (const float*)d_in[15];
  const float* kbv = (const float*)d_in[16];
  const float* vbv = (const float*)d_in[17];
  const float* obv = (const float*)d_in[18];
  const float* gamma = (const float*)d_in[19];
  const float* betag = (const float*)d_in[20];
  float* out = (float*)d_out;
  float* ws = (float*)d_ws;

  const size_t ND = (size_t)N_ROWS * DIM;  // 1,048,576 words

  // ---- region A [0, 4*ND words): Vb16 (qkv out) -> bt (QM out) -> plo
  us* Vb16 = (us*)ws;
  float* bt = ws;
  us* plo = (us*)ws;
  // ---- region B: all pointers CHAINED
  us* Qh = (us*)(ws + 4 * ND);                 // 4096*288 us
  us* Kh = Qh + (size_t)N_ROWS * LDQ;          // 4096*288 us
  us* Vtb = Kh + (size_t)N_ROWS * LDQ;         // 272*4096 us
  unsigned int* mbits = (unsigned int*)(Vtb + (size_t)272 * N_ROWS);
  float* kpart = (float*)(mbits + (size_t)N_ROWS * 128);
  float* ksum = kpart + 64 * DIM;
  float* c1a = ksum + DIM;
  float* cAa = c1a + N_ROWS;
  float* colB = cAa + N_ROWS;
  float* logy = colB + N_ROWS;
  float* xyzA = logy + N_ROWS;
  float* xyzB = xyzA + 3 * N_ROWS;
  float* gm = xyzB + 3 * N_ROWS;
  float* gi = gm + 8 * DIM;
  float* gpart = gi + 8 * DIM;
  float* psbase = gpart + 8 * GN_CHUNKS * 2 * DIM;
  float* paxlo = psbase + 16 * (size_t)N_ROWS;
  float* paxhi = paxlo + 8 * (size_t)N_ROWS * 3;
  us* Mb16 = (us*)(paxhi + 8 * (size_t)N_ROWS * 3);
  float* Pend = (float*)(Mb16 + 65536);  // P0
  // ---- overlay region [P0 ...): {bo, Ktb, Mp} XOR {phi}
  float* bo = Pend;                                  // ND f32
  us* Ktb = (us*)(bo + ND);                          // 256*4096 us
  float* Mp = (float*)(Ktb + (size_t)256 * N_ROWS);  // 8*65536 f32
  us* phi = (us*)Pend;                               // 8 splits * ND us
  us* xattb = Ktb;                                   // merge out (post-flash)
  const size_t P0w = (size_t)(Pend - ws);
  const size_t full16 = (P0w + 5 * ND) * 4;
  const int nsplit = (ws_size >= full16) ? 16 : 8;
  const int cps = N_ROWS / nsplit;
  float* bx = Pend + (size_t)(nsplit == 16 ? 4 : 2) * ND;  // layer out f32

  const int nseg = in_sizes[7] - 1;

  prep_kernel<<<16, 256, 0, stream>>>(yhat, logy);
  maskpack_kernel<<<65536, 256, 0, stream>>>(dmask, bmask, mbits);

  for (int l = 0; l < NLAYER; ++l) {
    const float* xin = (l == 0) ? x0 : bx;
    const float* xyz_in = (l == 0) ? xyz0 : ((l & 1) ? xyzB : xyzA);
    float* xyz_o = (l & 1) ? xyzA : xyzB;
    const size_t wo = (size_t)l * DIM * DIM;

    mfma_qkv_kernel<<<dim3(64, 4, 3), 256, 0, stream>>>(
        xin, qw + wo, kw + wo, vw + wo, qbv + l * DIM, kbv + l * DIM,
        vbv + l * DIM, Qh, Kh, Vb16);
    ksum_part_kernel<<<64, 256, 0, stream>>>(Kh, kpart);
    vt2_kernel<<<dim3(64, 4, 2), 256, 0, stream>>>(Kh, Vb16, Ktb, Vtb);
    ksum_red_kernel<<<1, 256, 0, stream>>>(kpart, ksum);
    mpart_mfma_kernel<<<dim3(4, 4, 8), 256, 0, stream>>>(Ktb, Mp);
    mreduce_kernel<<<256, 256, 0, stream>>>(Mp, Mb16);
    mfma_nt_kernel<<<dim3(64, 4), 256, 0, stream>>>(Qh, LDQ, Mb16, nullptr,
                                                    nullptr, nullptr, bt);
    stats_kernel<<<1024, 256, 0, stream>>>(Qh, Kh, Vtb, bt, ksum, xyz_in, logy,
                                           tptr, bwp, usestdp, c1a, cAa, colB);
    flash5_kernel<<<dim3(nsplit, 32), 256, 0, stream>>>(
        Qh, Kh, Vtb, colB, c1a, cAa, mbits, bwp, selfdp, plo, phi, psbase,
        paxlo, paxhi, cps);
    merge_kernel<<<1024, 256, 0, stream>>>(plo, phi, psbase, paxlo, paxhi,
                                           xyz_in, betap, xattb, xyz_o,
                                           nsplit);
    mfma_nt_kernel<<<dim3(64, 4), 256, 0, stream>>>(
        xattb, DIM, nullptr, ow + wo, obv + l * DIM, xin, bo);
    gn_part_kernel<<<dim3(nseg, GN_CHUNKS), 256, 0, stream>>>(bo, cums, gpart);
    gn_red_kernel<<<nseg, 256, 0, stream>>>(gpart, cums, gm, gi);
    gn_apply_kernel<<<1024, 256, 0, stream>>>(
        bo, gamma + (size_t)l * DIM, betag + (size_t)l * DIM, cums, nseg, gm,
        gi, bx, (l == NLAYER - 1) ? out : nullptr);
  }
}